// Round 3
// baseline (379.314 us; speedup 1.0000x reference)
//
#include <hip/hip_runtime.h>

// Block-circulant matmul via FFT, round 6: real-pair packing.
// Each block owns TWO batch rows packed as ONE complex signal z = x0 + i*x1:
//   - forward: 16 complex FFT-256 per block (was 32 real-ish FFTs)
//   - matmul:  unpack X0 = (Z(f)+conj(Z(-f))), X1 = -i(Z(f)-conj(Z(-f)))
//              (the 1/2 factors fold into the final 1/512 scale), multiply by
//              Hc(f) per (i,j), repack W = Y0 + i*Y1 at f and 256-f using the
//              conj symmetry of Y0,Y1 individually.
//   - inverse: ONE complex iFFT; Re -> row0, Im -> row1.
// This halves FFT VALU work AND halves LDS (76 -> 38 KiB): 4 blocks/CU,
// 16 waves/CU (4/SIMD) vs 8, and halves FFT-side LDS traffic/bank conflicts.
// Matmul FMA count unchanged; unpack costs 4 adds per j per thread.
// Wave-owned regions: each wave loads + FFTs only its own 4 FFT regions, so
// load->fft->scatter and ifft->store need NO barriers (same-wave DS order).
// Only 3 barriers/block (around the cross-wave frequency matmul).
// LDS: Ar/Ai [16*304] floats = 38 KiB total; phys() swizzle keeps b32 phases
// <=2-way.

#define TWO_PI 6.283185307179586f
constexpr int RS = 304;   // region stride (mod 32 == 16 -> 2-way across regions)

__device__ __forceinline__ int phys(int a) { return a + ((a >> 5) << 2); }

// (vr,vi) *= e^{-i*SGN*alpha}, where (c,s) = (cos alpha, sin alpha)
template<int SGN>
__device__ __forceinline__ void twmul(float& vr, float& vi, float c, float s)
{
    float r = vr * c + SGN * (vi * s);
    float i = vi * c - SGN * (vr * s);
    vr = r; vi = i;
}

// Pair 1 = DIF stages D=64 (butterfly over k, twiddle angle (th+pi*m/8)*r)
// and D=16 (butterfly over m, twiddle angle 4*th*r), th = 2*pi*u/256.
// Elements: position u + 16m + 64k <-> register s = m + 4k. Complex in/out.
template<int SGN>
__device__ __forceinline__ void pair1(float* __restrict__ Ar, float* __restrict__ Ai,
                                      int base, int u)
{
    float xr[16], xi[16];
#pragma unroll
    for (int s = 0; s < 16; ++s) {
        int a = base + phys(u + 16 * s);
        xr[s] = Ar[a];
        xi[s] = Ai[a];
    }
    float su, cu;
    __sincosf((float)u * (TWO_PI / 256.f), &su, &cu);
    const float CM[4] = {1.f, 0.92387953f, 0.70710678f, 0.38268343f};
    const float SM[4] = {0.f, 0.38268343f, 0.70710678f, 0.92387953f};
    float c1[4], s1[4], c2[4], s2[4], c3[4], s3[4];
#pragma unroll
    for (int m = 0; m < 4; ++m) {
        c1[m] = cu * CM[m] - su * SM[m];
        s1[m] = su * CM[m] + cu * SM[m];
        c2[m] = c1[m] * c1[m] - s1[m] * s1[m];
        s2[m] = 2.f * c1[m] * s1[m];
        c3[m] = c2[m] * c1[m] - s2[m] * s1[m];
        s3[m] = s2[m] * c1[m] + c2[m] * s1[m];
    }
    // stage A (D=64): A_k = x[m+4k]
#pragma unroll
    for (int m = 0; m < 4; ++m) {
        float t0r = xr[m] + xr[m + 8],       t0i = xi[m] + xi[m + 8];
        float t1r = xr[m] - xr[m + 8],       t1i = xi[m] - xi[m + 8];
        float t2r = xr[m + 4] + xr[m + 12],  t2i = xi[m + 4] + xi[m + 12];
        float t3r = xr[m + 4] - xr[m + 12],  t3i = xi[m + 4] - xi[m + 12];
        xr[m] = t0r + t2r;  xi[m] = t0i + t2i;
        float v1r = t1r + SGN * t3i, v1i = t1i - SGN * t3r;
        float v2r = t0r - t2r,       v2i = t0i - t2i;
        float v3r = t1r - SGN * t3i, v3i = t1i + SGN * t3r;
        twmul<SGN>(v1r, v1i, c1[m], s1[m]);
        twmul<SGN>(v2r, v2i, c2[m], s2[m]);
        twmul<SGN>(v3r, v3i, c3[m], s3[m]);
        xr[m + 4]  = v1r; xi[m + 4]  = v1i;
        xr[m + 8]  = v2r; xi[m + 8]  = v2i;
        xr[m + 12] = v3r; xi[m + 12] = v3i;
    }
    // stage B (D=16): A_m = x[4k+m], twiddle angles 4th, 8th, 12th
    float cb1 = cu * cu - su * su, sb1 = 2.f * cu * su;                  // 2th
    { float c = cb1, s = sb1; cb1 = c * c - s * s; sb1 = 2.f * c * s; }  // 4th
    float cb2 = cb1 * cb1 - sb1 * sb1, sb2 = 2.f * cb1 * sb1;            // 8th
    float cb3 = cb2 * cb1 - sb2 * sb1, sb3 = sb2 * cb1 + cb2 * sb1;      // 12th
#pragma unroll
    for (int k = 0; k < 4; ++k) {
        int s0 = 4 * k;
        float t0r = xr[s0] + xr[s0 + 2],     t0i = xi[s0] + xi[s0 + 2];
        float t1r = xr[s0] - xr[s0 + 2],     t1i = xi[s0] - xi[s0 + 2];
        float t2r = xr[s0 + 1] + xr[s0 + 3], t2i = xi[s0 + 1] + xi[s0 + 3];
        float t3r = xr[s0 + 1] - xr[s0 + 3], t3i = xi[s0 + 1] - xi[s0 + 3];
        xr[s0] = t0r + t2r;  xi[s0] = t0i + t2i;
        float v1r = t1r + SGN * t3i, v1i = t1i - SGN * t3r;
        float v2r = t0r - t2r,       v2i = t0i - t2i;
        float v3r = t1r - SGN * t3i, v3i = t1i + SGN * t3r;
        twmul<SGN>(v1r, v1i, cb1, sb1);
        twmul<SGN>(v2r, v2i, cb2, sb2);
        twmul<SGN>(v3r, v3i, cb3, sb3);
        xr[s0 + 1] = v1r; xi[s0 + 1] = v1i;
        xr[s0 + 2] = v2r; xi[s0 + 2] = v2i;
        xr[s0 + 3] = v3r; xi[s0 + 3] = v3i;
    }
#pragma unroll
    for (int s = 0; s < 16; ++s) {
        int a = base + phys(u + 16 * s);
        Ar[a] = xr[s]; Ai[a] = xi[s];
    }
}

// Pair 2 = DIF stages D=4 (butterfly over m, s=q+4m, twiddle angle pi*q*r/8,
// compile-time) and D=1 (butterfly over contiguous quad, no twiddle).
// Elements: position 16u + s (contiguous -> float4 LDS I/O). Complex in/out.
// STORE_REV: scatter outputs to rev4(position) (natural-order spectrum).
template<int SGN, bool STORE_REV>
__device__ __forceinline__ void pair2(float* __restrict__ Ar, float* __restrict__ Ai,
                                      int base, int u)
{
    int a0 = base + 16 * u + ((u >> 1) << 2);   // == base + phys(16u), contiguous run
    float xr[16], xi[16];
#pragma unroll
    for (int v = 0; v < 4; ++v) {
        float4 vr = *(const float4*)(Ar + a0 + 4 * v);
        float4 vi = *(const float4*)(Ai + a0 + 4 * v);
        xr[4 * v] = vr.x; xr[4 * v + 1] = vr.y; xr[4 * v + 2] = vr.z; xr[4 * v + 3] = vr.w;
        xi[4 * v] = vi.x; xi[4 * v + 1] = vi.y; xi[4 * v + 2] = vi.z; xi[4 * v + 3] = vi.w;
    }
    // stage C (D=4): A_m = x[q+4m], twiddle (c,s) of pi*q*r/8
    const float CQ[4][4] = {
        {1.f, 1.f, 1.f, 1.f},
        {1.f, 0.92387953f, 0.70710678f, 0.38268343f},
        {1.f, 0.70710678f, 0.f, -0.70710678f},
        {1.f, 0.38268343f, -0.70710678f, -0.92387953f}};
    const float SQ[4][4] = {
        {0.f, 0.f, 0.f, 0.f},
        {0.f, 0.38268343f, 0.70710678f, 0.92387953f},
        {0.f, 0.70710678f, 1.f, 0.70710678f},
        {0.f, 0.92387953f, 0.70710678f, -0.38268343f}};
#pragma unroll
    for (int q = 0; q < 4; ++q) {
        float t0r = xr[q] + xr[q + 8],       t0i = xi[q] + xi[q + 8];
        float t1r = xr[q] - xr[q + 8],       t1i = xi[q] - xi[q + 8];
        float t2r = xr[q + 4] + xr[q + 12],  t2i = xi[q + 4] + xi[q + 12];
        float t3r = xr[q + 4] - xr[q + 12],  t3i = xi[q + 4] - xi[q + 12];
        xr[q] = t0r + t2r;  xi[q] = t0i + t2i;
        float v1r = t1r + SGN * t3i, v1i = t1i - SGN * t3r;
        float v2r = t0r - t2r,       v2i = t0i - t2i;
        float v3r = t1r - SGN * t3i, v3i = t1i + SGN * t3r;
        twmul<SGN>(v1r, v1i, CQ[q][1], SQ[q][1]);
        twmul<SGN>(v2r, v2i, CQ[q][2], SQ[q][2]);
        twmul<SGN>(v3r, v3i, CQ[q][3], SQ[q][3]);
        xr[q + 4]  = v1r; xi[q + 4]  = v1i;
        xr[q + 8]  = v2r; xi[q + 8]  = v2i;
        xr[q + 12] = v3r; xi[q + 12] = v3i;
    }
    // stage D (D=1): contiguous quads, no twiddle
#pragma unroll
    for (int g = 0; g < 4; ++g) {
        int s0 = 4 * g;
        float t0r = xr[s0] + xr[s0 + 2],     t1r = xr[s0] - xr[s0 + 2];
        float t2r = xr[s0 + 1] + xr[s0 + 3], t3r = xr[s0 + 1] - xr[s0 + 3];
        float t0i = xi[s0] + xi[s0 + 2],     t1i = xi[s0] - xi[s0 + 2];
        float t2i = xi[s0 + 1] + xi[s0 + 3], t3i = xi[s0 + 1] - xi[s0 + 3];
        xr[s0]     = t0r + t2r;  xi[s0]     = t0i + t2i;
        xr[s0 + 1] = t1r + SGN * t3i;  xi[s0 + 1] = t1i - SGN * t3r;
        xr[s0 + 2] = t0r - t2r;        xi[s0 + 2] = t0i - t2i;
        xr[s0 + 3] = t1r - SGN * t3i;  xi[s0 + 3] = t1i + SGN * t3r;
    }
    if (STORE_REV) {
        int q2 = (u >> 2) + ((u & 3) << 2);
#pragma unroll
        for (int s = 0; s < 16; ++s) {
            int dest = q2 + ((s >> 2) << 4) + ((s & 3) << 6);   // rev4(16u+s)
            int a = base + phys(dest);
            Ar[a] = xr[s]; Ai[a] = xi[s];
        }
    } else {
#pragma unroll
        for (int v = 0; v < 4; ++v) {
            *(float4*)(Ar + a0 + 4 * v) = make_float4(xr[4*v], xr[4*v+1], xr[4*v+2], xr[4*v+3]);
            *(float4*)(Ai + a0 + 4 * v) = make_float4(xi[4*v], xi[4*v+1], xi[4*v+2], xi[4*v+3]);
        }
    }
}

// Wc4[i][jc][f] = float4(Hc[f][i][2jc].re,.im, Hc[f][i][2jc+1].re,.im),
// f = 0..128 (pad 132), Hc = conj(FFT_256(W[i,j,:])). 270 KB in d_ws.
__global__ __launch_bounds__(256) void wfft_kernel(const float* __restrict__ W,
                                                   float* __restrict__ Wc4)
{
    __shared__ float wblk[256];
    __shared__ float tabc[256], tabs[256];
    int t   = threadIdx.x;                 // t = frequency f
    int blk = blockIdx.x;                  // blk = i*16 + j
    wblk[t] = W[blk * 256 + t];
    float s, c;
    __sincosf((float)t * (TWO_PI / 256.f), &s, &c);
    tabc[t] = c; tabs[t] = s;
    __syncthreads();
    if (t <= 128) {
        float ar = 0.f, ai = 0.f;
        for (int cc = 0; cc < 256; ++cc) {
            int idx = (t * cc) & 255;
            float wv = wblk[cc];
            ar = fmaf(wv, tabc[idx], ar);
            ai = fmaf(wv, tabs[idx], ai);
        }
        int i = blk >> 4, j = blk & 15;
        int flat = ((i * 8 + (j >> 1)) * 132 + t) * 4 + ((j & 1) << 1);
        Wc4[flat]     = ar;
        Wc4[flat + 1] = ai;
    }
}

__global__ __launch_bounds__(256, 4) void bc_kernel(const float* __restrict__ x,
                                                    const float* __restrict__ d,
                                                    const float* __restrict__ bias,
                                                    const float* __restrict__ Wc4,
                                                    float* __restrict__ out)
{
    __shared__ float Ar[16 * RS], Ai[16 * RS];   // 38 KiB total -> 4 blocks/CU
    int t  = threadIdx.x;
    int b0 = blockIdx.x * 2;               // rows b0 (real part), b0+1 (imag part)
    int w = t >> 6, l = t & 63;
    int u = t & 15;
    int base = (t >> 4) * RS;              // region = 4w + (l>>4), wave-owned

    // ---- load: z_j = x0_j*d + i*x1_j*d, wave w loads its own regions 4w..4w+3
    const float4* d4 = (const float4*)d;
    const float4* x40 = (const float4*)(x + (size_t)b0 * 4096);
    const float4* x41 = (const float4*)(x + (size_t)(b0 + 1) * 4096);
#pragma unroll
    for (int it = 0; it < 4; ++it) {
        int idx = 256 * w + 64 * it + l;
        float4 dv = d4[idx];
        float4 v0 = x40[idx];
        float4 v1 = x41[idx];
        int a = (4 * w + it) * RS + 4 * l + ((l >> 3) << 2);   // phys(4l)
        *(float4*)(Ar + a) = make_float4(v0.x * dv.x, v0.y * dv.y, v0.z * dv.z, v0.w * dv.w);
        *(float4*)(Ai + a) = make_float4(v1.x * dv.x, v1.y * dv.y, v1.z * dv.z, v1.w * dv.w);
    }
    // no barrier: regions are wave-private, DS ops in-order within a wave

    pair1<1>(Ar, Ai, base, u);
    pair2<1, true>(Ar, Ai, base, u);           // scatter -> natural-order spectrum
    __syncthreads();                           // BAR 1: matmul reads cross-wave

    // ---- frequency matmul with unpack/repack: f = t&127, i-half = t>>7;
    //      f=128 handled by lanes t=64..79 (wave 1).
    {
        int f  = t & 127;
        int pf = phys(f);
        int pc = phys((256 - f) & 255);
        float zr[16], zi[16], z2r[16], z2i[16];
#pragma unroll
        for (int j = 0; j < 16; ++j) {
            zr[j]  = Ar[j * RS + pf];  zi[j]  = Ai[j * RS + pf];
            z2r[j] = Ar[j * RS + pc];  z2i[j] = Ai[j * RS + pc];
        }
        bool x128 = (t >= 64 && t < 80);       // wave-1 lanes 0..15 also own f=128
        int p8 = phys(128);
        float z8r[16], z8i[16];
        if (x128) {
#pragma unroll
            for (int j = 0; j < 16; ++j) {     // broadcast reads (same addr per lane)
                z8r[j] = Ar[j * RS + p8];
                z8i[j] = Ai[j * RS + p8];
            }
        }
        __syncthreads();                       // BAR 2: all reads before writes

        // unpack in place (2x convention; folded into final 1/512 scale):
        // X0 = Z(f)+conj(Z(-f)), X1 = -i*(Z(f)-conj(Z(-f)))
#pragma unroll
        for (int j = 0; j < 16; ++j) {
            float a = zr[j], b = zi[j], c = z2r[j], dd = z2i[j];
            zr[j]  = a + c;    // X0r
            zi[j]  = b - dd;   // X0i
            z2r[j] = b + dd;   // X1r
            z2i[j] = c - a;    // X1i
        }
        const float4* wb = (const float4*)Wc4;
        int ib = (t >> 7) * 8;
#pragma unroll
        for (int io = 0; io < 8; ++io) {
            int i = ib + io;
            float yr0 = 0.f, yi0 = 0.f, yr1 = 0.f, yi1 = 0.f;
#pragma unroll
            for (int jc = 0; jc < 8; ++jc) {
                float4 wv = wb[(i * 8 + jc) * 132 + f];
                int j0 = 2 * jc;
                yr0 = fmaf(zr[j0], wv.x, yr0);  yr0 = fmaf(-zi[j0], wv.y, yr0);
                yi0 = fmaf(zr[j0], wv.y, yi0);  yi0 = fmaf(zi[j0], wv.x, yi0);
                yr1 = fmaf(z2r[j0], wv.x, yr1); yr1 = fmaf(-z2i[j0], wv.y, yr1);
                yi1 = fmaf(z2r[j0], wv.y, yi1); yi1 = fmaf(z2i[j0], wv.x, yi1);
                yr0 = fmaf(zr[j0+1], wv.z, yr0);  yr0 = fmaf(-zi[j0+1], wv.w, yr0);
                yi0 = fmaf(zr[j0+1], wv.w, yi0);  yi0 = fmaf(zi[j0+1], wv.z, yi0);
                yr1 = fmaf(z2r[j0+1], wv.z, yr1); yr1 = fmaf(-z2i[j0+1], wv.w, yr1);
                yi1 = fmaf(z2r[j0+1], wv.w, yi1); yi1 = fmaf(z2i[j0+1], wv.z, yi1);
            }
            // repack: W(f) = Y0 + i*Y1;  W(256-f) = conj(Y0) + i*conj(Y1)
            Ar[i * RS + pf] = yr0 - yi1;
            Ai[i * RS + pf] = yi0 + yr1;
            if (f >= 1) {
                Ar[i * RS + pc] = yr0 + yi1;
                Ai[i * RS + pc] = yr1 - yi0;
            }
        }
        if (x128) {                            // f=128: X0 = (2*z8r, 0), X1 = (2*z8i, 0)
            int i = t - 64;
            float yr0 = 0.f, yi0 = 0.f, yr1 = 0.f, yi1 = 0.f;
#pragma unroll
            for (int jc = 0; jc < 8; ++jc) {
                float4 wv = wb[(i * 8 + jc) * 132 + 128];
                int j0 = 2 * jc;
                yr0 = fmaf(z8r[j0], wv.x, yr0);   yi0 = fmaf(z8r[j0], wv.y, yi0);
                yr1 = fmaf(z8i[j0], wv.x, yr1);   yi1 = fmaf(z8i[j0], wv.y, yi1);
                yr0 = fmaf(z8r[j0+1], wv.z, yr0); yi0 = fmaf(z8r[j0+1], wv.w, yi0);
                yr1 = fmaf(z8i[j0+1], wv.z, yr1); yi1 = fmaf(z8i[j0+1], wv.w, yi1);
            }
            Ar[i * RS + p8] = 2.f * (yr0 - yi1);
            Ai[i * RS + p8] = 2.f * (yi0 + yr1);
        }
    }
    __syncthreads();                           // BAR 3

    pair1<-1>(Ar, Ai, base, u);
    pair2<-1, false>(Ar, Ai, base, u);         // full complex out, contiguous store
    // no barrier: gather below reads own-wave regions only

    // ---- store: gather rev4 positions; Re -> row b0, Im -> row b0+1
    const float4* b4 = (const float4*)bias;
    float* o0 = out + (size_t)b0 * 4096;
    float* o1 = out + (size_t)(b0 + 1) * 4096;
    int dbase = ((l >> 4) & 3) + (((l >> 2) & 3) << 2) + ((l & 3) << 4);
#pragma unroll
    for (int it = 0; it < 4; ++it) {
        int idx = 256 * w + 64 * it + l;
        int rb  = (4 * w + it) * RS;
        float v0[4], v1[4];
#pragma unroll
        for (int e = 0; e < 4; ++e) {
            int a = rb + phys(dbase + (e << 6));   // rev4(4l+e)
            v0[e] = Ar[a];
            v1[e] = Ai[a];
        }
        float4 bv = b4[idx];
        float4 ov0, ov1;
        ov0.x = v0[0] * (1.f / 512.f) + bv.x;
        ov0.y = v0[1] * (1.f / 512.f) + bv.y;
        ov0.z = v0[2] * (1.f / 512.f) + bv.z;
        ov0.w = v0[3] * (1.f / 512.f) + bv.w;
        ov1.x = v1[0] * (1.f / 512.f) + bv.x;
        ov1.y = v1[1] * (1.f / 512.f) + bv.y;
        ov1.z = v1[2] * (1.f / 512.f) + bv.z;
        ov1.w = v1[3] * (1.f / 512.f) + bv.w;
        ((float4*)o0)[idx] = ov0;
        ((float4*)o1)[idx] = ov1;
    }
}

extern "C" void kernel_launch(void* const* d_in, const int* in_sizes, int n_in,
                              void* d_out, int out_size, void* d_ws, size_t ws_size,
                              hipStream_t stream)
{
    const float* x    = (const float*)d_in[0];   // (8192, 4096)
    const float* W    = (const float*)d_in[1];   // (16, 16, 256)
    const float* d    = (const float*)d_in[2];   // (4096,)
    const float* bias = (const float*)d_in[3];   // (4096,)
    float* out = (float*)d_out;
    float* Wc4 = (float*)d_ws;                   // [16][8][132] float4 = 270 KB

    wfft_kernel<<<256, 256, 0, stream>>>(W, Wc4);
    bc_kernel<<<4096, 256, 0, stream>>>(x, d, bias, Wc4, out);
}

// Round 5
// 316.389 us; speedup vs baseline: 1.1989x; 1.1989x over previous
//
#include <hip/hip_runtime.h>

// Block-circulant matmul via FFT, round 7 (resubmit — GPU acquisition timed
// out, kernel never measured): real-pair packing, spill fix.
// Round 6 regression root cause (from counters): __launch_bounds__(256,4) is
// only a MIN waves/EU -> allocator chased 8 waves/EU (VGPR=64) and spilled the
// matmul live set to scratch (WRITE_SIZE 439MB vs 131MB compulsory, VALUBusy
// 54->22%). Fixes:
//  (1) amdgpu_waves_per_eu(4,4) pins exactly 4 waves/EU -> 128-VGPR budget.
//  (2) f=128 lanes read the phys(128) spectrum column AFTER BAR2 straight
//      from LDS (that column is written by no repack thread: pf covers
//      phys(0..127), pc covers phys(129..255)) -> saves 32 live VGPRs that
//      round 6 held across the barrier.
// Algorithm unchanged from round 6: two rows packed z = x0*d + i*x1*d, one
// complex FFT-256 per j (16/block), unpack X0/X1 via conj symmetry at the
// matmul, repack W = Y0 + i*Y1, one complex iFFT, Re->row0 / Im->row1.
// LDS: Ar/Ai [16*304] floats = 38 KiB -> 4 blocks/CU; 3 barriers/block;
// phys() swizzle keeps b32 phases <=2-way.

#define TWO_PI 6.283185307179586f
constexpr int RS = 304;   // region stride (mod 32 == 16 -> 2-way across regions)

__device__ __forceinline__ int phys(int a) { return a + ((a >> 5) << 2); }

// (vr,vi) *= e^{-i*SGN*alpha}, where (c,s) = (cos alpha, sin alpha)
template<int SGN>
__device__ __forceinline__ void twmul(float& vr, float& vi, float c, float s)
{
    float r = vr * c + SGN * (vi * s);
    float i = vi * c - SGN * (vr * s);
    vr = r; vi = i;
}

// Pair 1 = DIF stages D=64 (butterfly over k, twiddle angle (th+pi*m/8)*r)
// and D=16 (butterfly over m, twiddle angle 4*th*r), th = 2*pi*u/256.
// Elements: position u + 16m + 64k <-> register s = m + 4k. Complex in/out.
template<int SGN>
__device__ __forceinline__ void pair1(float* __restrict__ Ar, float* __restrict__ Ai,
                                      int base, int u)
{
    float xr[16], xi[16];
#pragma unroll
    for (int s = 0; s < 16; ++s) {
        int a = base + phys(u + 16 * s);
        xr[s] = Ar[a];
        xi[s] = Ai[a];
    }
    float su, cu;
    __sincosf((float)u * (TWO_PI / 256.f), &su, &cu);
    const float CM[4] = {1.f, 0.92387953f, 0.70710678f, 0.38268343f};
    const float SM[4] = {0.f, 0.38268343f, 0.70710678f, 0.92387953f};
    float c1[4], s1[4], c2[4], s2[4], c3[4], s3[4];
#pragma unroll
    for (int m = 0; m < 4; ++m) {
        c1[m] = cu * CM[m] - su * SM[m];
        s1[m] = su * CM[m] + cu * SM[m];
        c2[m] = c1[m] * c1[m] - s1[m] * s1[m];
        s2[m] = 2.f * c1[m] * s1[m];
        c3[m] = c2[m] * c1[m] - s2[m] * s1[m];
        s3[m] = s2[m] * c1[m] + c2[m] * s1[m];
    }
    // stage A (D=64): A_k = x[m+4k]
#pragma unroll
    for (int m = 0; m < 4; ++m) {
        float t0r = xr[m] + xr[m + 8],       t0i = xi[m] + xi[m + 8];
        float t1r = xr[m] - xr[m + 8],       t1i = xi[m] - xi[m + 8];
        float t2r = xr[m + 4] + xr[m + 12],  t2i = xi[m + 4] + xi[m + 12];
        float t3r = xr[m + 4] - xr[m + 12],  t3i = xi[m + 4] - xi[m + 12];
        xr[m] = t0r + t2r;  xi[m] = t0i + t2i;
        float v1r = t1r + SGN * t3i, v1i = t1i - SGN * t3r;
        float v2r = t0r - t2r,       v2i = t0i - t2i;
        float v3r = t1r - SGN * t3i, v3i = t1i + SGN * t3r;
        twmul<SGN>(v1r, v1i, c1[m], s1[m]);
        twmul<SGN>(v2r, v2i, c2[m], s2[m]);
        twmul<SGN>(v3r, v3i, c3[m], s3[m]);
        xr[m + 4]  = v1r; xi[m + 4]  = v1i;
        xr[m + 8]  = v2r; xi[m + 8]  = v2i;
        xr[m + 12] = v3r; xi[m + 12] = v3i;
    }
    // stage B (D=16): A_m = x[4k+m], twiddle angles 4th, 8th, 12th
    float cb1 = cu * cu - su * su, sb1 = 2.f * cu * su;                  // 2th
    { float c = cb1, s = sb1; cb1 = c * c - s * s; sb1 = 2.f * c * s; }  // 4th
    float cb2 = cb1 * cb1 - sb1 * sb1, sb2 = 2.f * cb1 * sb1;            // 8th
    float cb3 = cb2 * cb1 - sb2 * sb1, sb3 = sb2 * cb1 + cb2 * sb1;      // 12th
#pragma unroll
    for (int k = 0; k < 4; ++k) {
        int s0 = 4 * k;
        float t0r = xr[s0] + xr[s0 + 2],     t0i = xi[s0] + xi[s0 + 2];
        float t1r = xr[s0] - xr[s0 + 2],     t1i = xi[s0] - xi[s0 + 2];
        float t2r = xr[s0 + 1] + xr[s0 + 3], t2i = xi[s0 + 1] + xi[s0 + 3];
        float t3r = xr[s0 + 1] - xr[s0 + 3], t3i = xi[s0 + 1] - xi[s0 + 3];
        xr[s0] = t0r + t2r;  xi[s0] = t0i + t2i;
        float v1r = t1r + SGN * t3i, v1i = t1i - SGN * t3r;
        float v2r = t0r - t2r,       v2i = t0i - t2i;
        float v3r = t1r - SGN * t3i, v3i = t1i + SGN * t3r;
        twmul<SGN>(v1r, v1i, cb1, sb1);
        twmul<SGN>(v2r, v2i, cb2, sb2);
        twmul<SGN>(v3r, v3i, cb3, sb3);
        xr[s0 + 1] = v1r; xi[s0 + 1] = v1i;
        xr[s0 + 2] = v2r; xi[s0 + 2] = v2i;
        xr[s0 + 3] = v3r; xi[s0 + 3] = v3i;
    }
#pragma unroll
    for (int s = 0; s < 16; ++s) {
        int a = base + phys(u + 16 * s);
        Ar[a] = xr[s]; Ai[a] = xi[s];
    }
}

// Pair 2 = DIF stages D=4 (butterfly over m, s=q+4m, twiddle angle pi*q*r/8,
// compile-time) and D=1 (butterfly over contiguous quad, no twiddle).
// Elements: position 16u + s (contiguous -> float4 LDS I/O). Complex in/out.
// STORE_REV: scatter outputs to rev4(position) (natural-order spectrum).
template<int SGN, bool STORE_REV>
__device__ __forceinline__ void pair2(float* __restrict__ Ar, float* __restrict__ Ai,
                                      int base, int u)
{
    int a0 = base + 16 * u + ((u >> 1) << 2);   // == base + phys(16u), contiguous run
    float xr[16], xi[16];
#pragma unroll
    for (int v = 0; v < 4; ++v) {
        float4 vr = *(const float4*)(Ar + a0 + 4 * v);
        float4 vi = *(const float4*)(Ai + a0 + 4 * v);
        xr[4 * v] = vr.x; xr[4 * v + 1] = vr.y; xr[4 * v + 2] = vr.z; xr[4 * v + 3] = vr.w;
        xi[4 * v] = vi.x; xi[4 * v + 1] = vi.y; xi[4 * v + 2] = vi.z; xi[4 * v + 3] = vi.w;
    }
    // stage C (D=4): A_m = x[q+4m], twiddle (c,s) of pi*q*r/8
    const float CQ[4][4] = {
        {1.f, 1.f, 1.f, 1.f},
        {1.f, 0.92387953f, 0.70710678f, 0.38268343f},
        {1.f, 0.70710678f, 0.f, -0.70710678f},
        {1.f, 0.38268343f, -0.70710678f, -0.92387953f}};
    const float SQ[4][4] = {
        {0.f, 0.f, 0.f, 0.f},
        {0.f, 0.38268343f, 0.70710678f, 0.92387953f},
        {0.f, 0.70710678f, 1.f, 0.70710678f},
        {0.f, 0.92387953f, 0.70710678f, -0.38268343f}};
#pragma unroll
    for (int q = 0; q < 4; ++q) {
        float t0r = xr[q] + xr[q + 8],       t0i = xi[q] + xi[q + 8];
        float t1r = xr[q] - xr[q + 8],       t1i = xi[q] - xi[q + 8];
        float t2r = xr[q + 4] + xr[q + 12],  t2i = xi[q + 4] + xi[q + 12];
        float t3r = xr[q + 4] - xr[q + 12],  t3i = xi[q + 4] - xi[q + 12];
        xr[q] = t0r + t2r;  xi[q] = t0i + t2i;
        float v1r = t1r + SGN * t3i, v1i = t1i - SGN * t3r;
        float v2r = t0r - t2r,       v2i = t0i - t2i;
        float v3r = t1r - SGN * t3i, v3i = t1i + SGN * t3r;
        twmul<SGN>(v1r, v1i, CQ[q][1], SQ[q][1]);
        twmul<SGN>(v2r, v2i, CQ[q][2], SQ[q][2]);
        twmul<SGN>(v3r, v3i, CQ[q][3], SQ[q][3]);
        xr[q + 4]  = v1r; xi[q + 4]  = v1i;
        xr[q + 8]  = v2r; xi[q + 8]  = v2i;
        xr[q + 12] = v3r; xi[q + 12] = v3i;
    }
    // stage D (D=1): contiguous quads, no twiddle
#pragma unroll
    for (int g = 0; g < 4; ++g) {
        int s0 = 4 * g;
        float t0r = xr[s0] + xr[s0 + 2],     t1r = xr[s0] - xr[s0 + 2];
        float t2r = xr[s0 + 1] + xr[s0 + 3], t3r = xr[s0 + 1] - xr[s0 + 3];
        float t0i = xi[s0] + xi[s0 + 2],     t1i = xi[s0] - xi[s0 + 2];
        float t2i = xi[s0 + 1] + xi[s0 + 3], t3i = xi[s0 + 1] - xi[s0 + 3];
        xr[s0]     = t0r + t2r;  xi[s0]     = t0i + t2i;
        xr[s0 + 1] = t1r + SGN * t3i;  xi[s0 + 1] = t1i - SGN * t3r;
        xr[s0 + 2] = t0r - t2r;        xi[s0 + 2] = t0i - t2i;
        xr[s0 + 3] = t1r - SGN * t3i;  xi[s0 + 3] = t1i + SGN * t3r;
    }
    if (STORE_REV) {
        int q2 = (u >> 2) + ((u & 3) << 2);
#pragma unroll
        for (int s = 0; s < 16; ++s) {
            int dest = q2 + ((s >> 2) << 4) + ((s & 3) << 6);   // rev4(16u+s)
            int a = base + phys(dest);
            Ar[a] = xr[s]; Ai[a] = xi[s];
        }
    } else {
#pragma unroll
        for (int v = 0; v < 4; ++v) {
            *(float4*)(Ar + a0 + 4 * v) = make_float4(xr[4*v], xr[4*v+1], xr[4*v+2], xr[4*v+3]);
            *(float4*)(Ai + a0 + 4 * v) = make_float4(xi[4*v], xi[4*v+1], xi[4*v+2], xi[4*v+3]);
        }
    }
}

// Wc4[i][jc][f] = float4(Hc[f][i][2jc].re,.im, Hc[f][i][2jc+1].re,.im),
// f = 0..128 (pad 132), Hc = conj(FFT_256(W[i,j,:])). 270 KB in d_ws.
__global__ __launch_bounds__(256) void wfft_kernel(const float* __restrict__ W,
                                                   float* __restrict__ Wc4)
{
    __shared__ float wblk[256];
    __shared__ float tabc[256], tabs[256];
    int t   = threadIdx.x;                 // t = frequency f
    int blk = blockIdx.x;                  // blk = i*16 + j
    wblk[t] = W[blk * 256 + t];
    float s, c;
    __sincosf((float)t * (TWO_PI / 256.f), &s, &c);
    tabc[t] = c; tabs[t] = s;
    __syncthreads();
    if (t <= 128) {
        float ar = 0.f, ai = 0.f;
        for (int cc = 0; cc < 256; ++cc) {
            int idx = (t * cc) & 255;
            float wv = wblk[cc];
            ar = fmaf(wv, tabc[idx], ar);
            ai = fmaf(wv, tabs[idx], ai);
        }
        int i = blk >> 4, j = blk & 15;
        int flat = ((i * 8 + (j >> 1)) * 132 + t) * 4 + ((j & 1) << 1);
        Wc4[flat]     = ar;
        Wc4[flat + 1] = ai;
    }
}

__global__ __launch_bounds__(256)
__attribute__((amdgpu_waves_per_eu(4, 4)))
void bc_kernel(const float* __restrict__ x,
               const float* __restrict__ d,
               const float* __restrict__ bias,
               const float* __restrict__ Wc4,
               float* __restrict__ out)
{
    __shared__ float Ar[16 * RS], Ai[16 * RS];   // 38 KiB total -> 4 blocks/CU
    int t  = threadIdx.x;
    int b0 = blockIdx.x * 2;               // rows b0 (real part), b0+1 (imag part)
    int w = t >> 6, l = t & 63;
    int u = t & 15;
    int base = (t >> 4) * RS;              // region = 4w + (l>>4), wave-owned

    // ---- load: z_j = x0_j*d + i*x1_j*d, wave w loads its own regions 4w..4w+3
    const float4* d4 = (const float4*)d;
    const float4* x40 = (const float4*)(x + (size_t)b0 * 4096);
    const float4* x41 = (const float4*)(x + (size_t)(b0 + 1) * 4096);
#pragma unroll
    for (int it = 0; it < 4; ++it) {
        int idx = 256 * w + 64 * it + l;
        float4 dv = d4[idx];
        float4 v0 = x40[idx];
        float4 v1 = x41[idx];
        int a = (4 * w + it) * RS + 4 * l + ((l >> 3) << 2);   // phys(4l)
        *(float4*)(Ar + a) = make_float4(v0.x * dv.x, v0.y * dv.y, v0.z * dv.z, v0.w * dv.w);
        *(float4*)(Ai + a) = make_float4(v1.x * dv.x, v1.y * dv.y, v1.z * dv.z, v1.w * dv.w);
    }
    // no barrier: regions are wave-private, DS ops in-order within a wave

    pair1<1>(Ar, Ai, base, u);
    pair2<1, true>(Ar, Ai, base, u);           // scatter -> natural-order spectrum
    __syncthreads();                           // BAR 1: matmul reads cross-wave

    // ---- frequency matmul with unpack/repack: f = t&127, i-half = t>>7;
    //      f=128 handled by lanes t=64..79 AFTER BAR2 (phys(128) column is
    //      neither written nor read by any repack thread -> no reg preload).
    {
        int f  = t & 127;
        int pf = phys(f);
        int pc = phys((256 - f) & 255);
        float zr[16], zi[16], z2r[16], z2i[16];
#pragma unroll
        for (int j = 0; j < 16; ++j) {
            zr[j]  = Ar[j * RS + pf];  zi[j]  = Ai[j * RS + pf];
            z2r[j] = Ar[j * RS + pc];  z2i[j] = Ai[j * RS + pc];
        }
        __syncthreads();                       // BAR 2: all reads before writes

        // unpack in place (2x convention; folded into final 1/512 scale):
        // X0 = Z(f)+conj(Z(-f)), X1 = -i*(Z(f)-conj(Z(-f)))
#pragma unroll
        for (int j = 0; j < 16; ++j) {
            float a = zr[j], b = zi[j], c = z2r[j], dd = z2i[j];
            zr[j]  = a + c;    // X0r
            zi[j]  = b - dd;   // X0i
            z2r[j] = b + dd;   // X1r
            z2i[j] = c - a;    // X1i
        }
        const float4* wb = (const float4*)Wc4;
        int ib = (t >> 7) * 8;
#pragma unroll
        for (int io = 0; io < 8; ++io) {
            int i = ib + io;
            float yr0 = 0.f, yi0 = 0.f, yr1 = 0.f, yi1 = 0.f;
#pragma unroll
            for (int jc = 0; jc < 8; ++jc) {
                float4 wv = wb[(i * 8 + jc) * 132 + f];
                int j0 = 2 * jc;
                yr0 = fmaf(zr[j0], wv.x, yr0);  yr0 = fmaf(-zi[j0], wv.y, yr0);
                yi0 = fmaf(zr[j0], wv.y, yi0);  yi0 = fmaf(zi[j0], wv.x, yi0);
                yr1 = fmaf(z2r[j0], wv.x, yr1); yr1 = fmaf(-z2i[j0], wv.y, yr1);
                yi1 = fmaf(z2r[j0], wv.y, yi1); yi1 = fmaf(z2i[j0], wv.x, yi1);
                yr0 = fmaf(zr[j0+1], wv.z, yr0);  yr0 = fmaf(-zi[j0+1], wv.w, yr0);
                yi0 = fmaf(zr[j0+1], wv.w, yi0);  yi0 = fmaf(zi[j0+1], wv.z, yi0);
                yr1 = fmaf(z2r[j0+1], wv.z, yr1); yr1 = fmaf(-z2i[j0+1], wv.w, yr1);
                yi1 = fmaf(z2r[j0+1], wv.w, yi1); yi1 = fmaf(z2i[j0+1], wv.z, yi1);
            }
            // repack: W(f) = Y0 + i*Y1;  W(256-f) = conj(Y0) + i*conj(Y1)
            Ar[i * RS + pf] = yr0 - yi1;
            Ai[i * RS + pf] = yi0 + yr1;
            if (f >= 1) {
                Ar[i * RS + pc] = yr0 + yi1;
                Ai[i * RS + pc] = yr1 - yi0;
            }
        }
        if (t >= 64 && t < 80) {               // f=128: read+write phys(128) col,
            int i = t - 64;                    // untouched by any other thread here
            int p8 = phys(128);
            float yr0 = 0.f, yi0 = 0.f, yr1 = 0.f, yi1 = 0.f;
#pragma unroll
            for (int jc = 0; jc < 8; ++jc) {
                float4 wv = wb[(i * 8 + jc) * 132 + 128];
                int j0 = 2 * jc;
                float a0r = Ar[j0 * RS + p8],       a0i = Ai[j0 * RS + p8];
                float a1r = Ar[(j0 + 1) * RS + p8], a1i = Ai[(j0 + 1) * RS + p8];
                // X0 = 2*Re(Z), X1 = 2*Im(Z) at f=128 (factor 2 applied at store)
                yr0 = fmaf(a0r, wv.x, yr0);   yi0 = fmaf(a0r, wv.y, yi0);
                yr1 = fmaf(a0i, wv.x, yr1);   yi1 = fmaf(a0i, wv.y, yi1);
                yr0 = fmaf(a1r, wv.z, yr0);   yi0 = fmaf(a1r, wv.w, yi0);
                yr1 = fmaf(a1i, wv.z, yr1);   yi1 = fmaf(a1i, wv.w, yi1);
            }
            Ar[i * RS + p8] = 2.f * (yr0 - yi1);
            Ai[i * RS + p8] = 2.f * (yi0 + yr1);
        }
    }
    __syncthreads();                           // BAR 3

    pair1<-1>(Ar, Ai, base, u);
    pair2<-1, false>(Ar, Ai, base, u);         // full complex out, contiguous store
    // no barrier: gather below reads own-wave regions only

    // ---- store: gather rev4 positions; Re -> row b0, Im -> row b0+1
    const float4* b4 = (const float4*)bias;
    float* o0 = out + (size_t)b0 * 4096;
    float* o1 = out + (size_t)(b0 + 1) * 4096;
    int dbase = ((l >> 4) & 3) + (((l >> 2) & 3) << 2) + ((l & 3) << 4);
#pragma unroll
    for (int it = 0; it < 4; ++it) {
        int idx = 256 * w + 64 * it + l;
        int rb  = (4 * w + it) * RS;
        float v0[4], v1[4];
#pragma unroll
        for (int e = 0; e < 4; ++e) {
            int a = rb + phys(dbase + (e << 6));   // rev4(4l+e)
            v0[e] = Ar[a];
            v1[e] = Ai[a];
        }
        float4 bv = b4[idx];
        float4 ov0, ov1;
        ov0.x = v0[0] * (1.f / 512.f) + bv.x;
        ov0.y = v0[1] * (1.f / 512.f) + bv.y;
        ov0.z = v0[2] * (1.f / 512.f) + bv.z;
        ov0.w = v0[3] * (1.f / 512.f) + bv.w;
        ov1.x = v1[0] * (1.f / 512.f) + bv.x;
        ov1.y = v1[1] * (1.f / 512.f) + bv.y;
        ov1.z = v1[2] * (1.f / 512.f) + bv.z;
        ov1.w = v1[3] * (1.f / 512.f) + bv.w;
        ((float4*)o0)[idx] = ov0;
        ((float4*)o1)[idx] = ov1;
    }
}

extern "C" void kernel_launch(void* const* d_in, const int* in_sizes, int n_in,
                              void* d_out, int out_size, void* d_ws, size_t ws_size,
                              hipStream_t stream)
{
    const float* x    = (const float*)d_in[0];   // (8192, 4096)
    const float* W    = (const float*)d_in[1];   // (16, 16, 256)
    const float* d    = (const float*)d_in[2];   // (4096,)
    const float* bias = (const float*)d_in[3];   // (4096,)
    float* out = (float*)d_out;
    float* Wc4 = (float*)d_ws;                   // [16][8][132] float4 = 270 KB

    wfft_kernel<<<256, 256, 0, stream>>>(W, Wc4);
    bc_kernel<<<4096, 256, 0, stream>>>(x, d, bias, Wc4, out);
}

// Round 8
// 295.057 us; speedup vs baseline: 1.2856x; 1.0723x over previous
//
#include <hip/hip_runtime.h>

// Block-circulant matmul via FFT, round 8 (3rd resubmit — GPU acquisition
// timed out on every attempt; kernel never measured): real-pair packing,
// spill fix v2.
// Round 7 counters: amdgpu_waves_per_eu(4,4) did NOT raise the VGPR budget
// (VGPR_Count still 64); ~32 VGPRs/thread spilled (WRITE_SIZE 264MB vs 134MB
// compulsory = 4096 blocks x 32KB scratch). Round 5's kernel PROVED
// __launch_bounds__(256, 2) yields a sane allocation (108 VGPR, zero spill).
// Fix: use __launch_bounds__(256, 2). Occupancy needs no protection - LDS
// (38 KiB -> 4 blocks/CU = 4 waves/SIMD) is the binding runtime cap either way.
// Algorithm unchanged from round 6/7: two rows packed z = x0*d + i*x1*d, one
// complex FFT-256 per j (16/block), unpack X0/X1 via conj symmetry at the
// matmul, repack W = Y0 + i*Y1, one complex iFFT, Re->row0 / Im->row1.
// f=128 handled by lanes t=64..79 AFTER BAR2 straight from LDS (phys(128)
// column is written by no repack thread: pf covers phys(0..127), pc covers
// phys(129..255)) - keeps 32 VGPRs dead across the barrier.
// LDS: Ar/Ai [16*304] floats = 38 KiB; 3 barriers/block; phys() swizzle keeps
// b32 phases <=2-way.

#define TWO_PI 6.283185307179586f
constexpr int RS = 304;   // region stride (mod 32 == 16 -> 2-way across regions)

__device__ __forceinline__ int phys(int a) { return a + ((a >> 5) << 2); }

// (vr,vi) *= e^{-i*SGN*alpha}, where (c,s) = (cos alpha, sin alpha)
template<int SGN>
__device__ __forceinline__ void twmul(float& vr, float& vi, float c, float s)
{
    float r = vr * c + SGN * (vi * s);
    float i = vi * c - SGN * (vr * s);
    vr = r; vi = i;
}

// Pair 1 = DIF stages D=64 (butterfly over k, twiddle angle (th+pi*m/8)*r)
// and D=16 (butterfly over m, twiddle angle 4*th*r), th = 2*pi*u/256.
// Elements: position u + 16m + 64k <-> register s = m + 4k. Complex in/out.
template<int SGN>
__device__ __forceinline__ void pair1(float* __restrict__ Ar, float* __restrict__ Ai,
                                      int base, int u)
{
    float xr[16], xi[16];
#pragma unroll
    for (int s = 0; s < 16; ++s) {
        int a = base + phys(u + 16 * s);
        xr[s] = Ar[a];
        xi[s] = Ai[a];
    }
    float su, cu;
    __sincosf((float)u * (TWO_PI / 256.f), &su, &cu);
    const float CM[4] = {1.f, 0.92387953f, 0.70710678f, 0.38268343f};
    const float SM[4] = {0.f, 0.38268343f, 0.70710678f, 0.92387953f};
    float c1[4], s1[4], c2[4], s2[4], c3[4], s3[4];
#pragma unroll
    for (int m = 0; m < 4; ++m) {
        c1[m] = cu * CM[m] - su * SM[m];
        s1[m] = su * CM[m] + cu * SM[m];
        c2[m] = c1[m] * c1[m] - s1[m] * s1[m];
        s2[m] = 2.f * c1[m] * s1[m];
        c3[m] = c2[m] * c1[m] - s2[m] * s1[m];
        s3[m] = s2[m] * c1[m] + c2[m] * s1[m];
    }
    // stage A (D=64): A_k = x[m+4k]
#pragma unroll
    for (int m = 0; m < 4; ++m) {
        float t0r = xr[m] + xr[m + 8],       t0i = xi[m] + xi[m + 8];
        float t1r = xr[m] - xr[m + 8],       t1i = xi[m] - xi[m + 8];
        float t2r = xr[m + 4] + xr[m + 12],  t2i = xi[m + 4] + xi[m + 12];
        float t3r = xr[m + 4] - xr[m + 12],  t3i = xi[m + 4] - xi[m + 12];
        xr[m] = t0r + t2r;  xi[m] = t0i + t2i;
        float v1r = t1r + SGN * t3i, v1i = t1i - SGN * t3r;
        float v2r = t0r - t2r,       v2i = t0i - t2i;
        float v3r = t1r - SGN * t3i, v3i = t1i + SGN * t3r;
        twmul<SGN>(v1r, v1i, c1[m], s1[m]);
        twmul<SGN>(v2r, v2i, c2[m], s2[m]);
        twmul<SGN>(v3r, v3i, c3[m], s3[m]);
        xr[m + 4]  = v1r; xi[m + 4]  = v1i;
        xr[m + 8]  = v2r; xi[m + 8]  = v2i;
        xr[m + 12] = v3r; xi[m + 12] = v3i;
    }
    // stage B (D=16): A_m = x[4k+m], twiddle angles 4th, 8th, 12th
    float cb1 = cu * cu - su * su, sb1 = 2.f * cu * su;                  // 2th
    { float c = cb1, s = sb1; cb1 = c * c - s * s; sb1 = 2.f * c * s; }  // 4th
    float cb2 = cb1 * cb1 - sb1 * sb1, sb2 = 2.f * cb1 * sb1;            // 8th
    float cb3 = cb2 * cb1 - sb2 * sb1, sb3 = sb2 * cb1 + cb2 * sb1;      // 12th
#pragma unroll
    for (int k = 0; k < 4; ++k) {
        int s0 = 4 * k;
        float t0r = xr[s0] + xr[s0 + 2],     t0i = xi[s0] + xi[s0 + 2];
        float t1r = xr[s0] - xr[s0 + 2],     t1i = xi[s0] - xi[s0 + 2];
        float t2r = xr[s0 + 1] + xr[s0 + 3], t2i = xi[s0 + 1] + xi[s0 + 3];
        float t3r = xr[s0 + 1] - xr[s0 + 3], t3i = xi[s0 + 1] - xi[s0 + 3];
        xr[s0] = t0r + t2r;  xi[s0] = t0i + t2i;
        float v1r = t1r + SGN * t3i, v1i = t1i - SGN * t3r;
        float v2r = t0r - t2r,       v2i = t0i - t2i;
        float v3r = t1r - SGN * t3i, v3i = t1i + SGN * t3r;
        twmul<SGN>(v1r, v1i, cb1, sb1);
        twmul<SGN>(v2r, v2i, cb2, sb2);
        twmul<SGN>(v3r, v3i, cb3, sb3);
        xr[s0 + 1] = v1r; xi[s0 + 1] = v1i;
        xr[s0 + 2] = v2r; xi[s0 + 2] = v2i;
        xr[s0 + 3] = v3r; xi[s0 + 3] = v3i;
    }
#pragma unroll
    for (int s = 0; s < 16; ++s) {
        int a = base + phys(u + 16 * s);
        Ar[a] = xr[s]; Ai[a] = xi[s];
    }
}

// Pair 2 = DIF stages D=4 (butterfly over m, s=q+4m, twiddle angle pi*q*r/8,
// compile-time) and D=1 (butterfly over contiguous quad, no twiddle).
// Elements: position 16u + s (contiguous -> float4 LDS I/O). Complex in/out.
// STORE_REV: scatter outputs to rev4(position) (natural-order spectrum).
template<int SGN, bool STORE_REV>
__device__ __forceinline__ void pair2(float* __restrict__ Ar, float* __restrict__ Ai,
                                      int base, int u)
{
    int a0 = base + 16 * u + ((u >> 1) << 2);   // == base + phys(16u), contiguous run
    float xr[16], xi[16];
#pragma unroll
    for (int v = 0; v < 4; ++v) {
        float4 vr = *(const float4*)(Ar + a0 + 4 * v);
        float4 vi = *(const float4*)(Ai + a0 + 4 * v);
        xr[4 * v] = vr.x; xr[4 * v + 1] = vr.y; xr[4 * v + 2] = vr.z; xr[4 * v + 3] = vr.w;
        xi[4 * v] = vi.x; xi[4 * v + 1] = vi.y; xi[4 * v + 2] = vi.z; xi[4 * v + 3] = vi.w;
    }
    // stage C (D=4): A_m = x[q+4m], twiddle (c,s) of pi*q*r/8
    const float CQ[4][4] = {
        {1.f, 1.f, 1.f, 1.f},
        {1.f, 0.92387953f, 0.70710678f, 0.38268343f},
        {1.f, 0.70710678f, 0.f, -0.70710678f},
        {1.f, 0.38268343f, -0.70710678f, -0.92387953f}};
    const float SQ[4][4] = {
        {0.f, 0.f, 0.f, 0.f},
        {0.f, 0.38268343f, 0.70710678f, 0.92387953f},
        {0.f, 0.70710678f, 1.f, 0.70710678f},
        {0.f, 0.92387953f, 0.70710678f, -0.38268343f}};
#pragma unroll
    for (int q = 0; q < 4; ++q) {
        float t0r = xr[q] + xr[q + 8],       t0i = xi[q] + xi[q + 8];
        float t1r = xr[q] - xr[q + 8],       t1i = xi[q] - xi[q + 8];
        float t2r = xr[q + 4] + xr[q + 12],  t2i = xi[q + 4] + xi[q + 12];
        float t3r = xr[q + 4] - xr[q + 12],  t3i = xi[q + 4] - xi[q + 12];
        xr[q] = t0r + t2r;  xi[q] = t0i + t2i;
        float v1r = t1r + SGN * t3i, v1i = t1i - SGN * t3r;
        float v2r = t0r - t2r,       v2i = t0i - t2i;
        float v3r = t1r - SGN * t3i, v3i = t1i + SGN * t3r;
        twmul<SGN>(v1r, v1i, CQ[q][1], SQ[q][1]);
        twmul<SGN>(v2r, v2i, CQ[q][2], SQ[q][2]);
        twmul<SGN>(v3r, v3i, CQ[q][3], SQ[q][3]);
        xr[q + 4]  = v1r; xi[q + 4]  = v1i;
        xr[q + 8]  = v2r; xi[q + 8]  = v2i;
        xr[q + 12] = v3r; xi[q + 12] = v3i;
    }
    // stage D (D=1): contiguous quads, no twiddle
#pragma unroll
    for (int g = 0; g < 4; ++g) {
        int s0 = 4 * g;
        float t0r = xr[s0] + xr[s0 + 2],     t1r = xr[s0] - xr[s0 + 2];
        float t2r = xr[s0 + 1] + xr[s0 + 3], t3r = xr[s0 + 1] - xr[s0 + 3];
        float t0i = xi[s0] + xi[s0 + 2],     t1i = xi[s0] - xi[s0 + 2];
        float t2i = xi[s0 + 1] + xi[s0 + 3], t3i = xi[s0 + 1] - xi[s0 + 3];
        xr[s0]     = t0r + t2r;  xi[s0]     = t0i + t2i;
        xr[s0 + 1] = t1r + SGN * t3i;  xi[s0 + 1] = t1i - SGN * t3r;
        xr[s0 + 2] = t0r - t2r;        xi[s0 + 2] = t0i - t2i;
        xr[s0 + 3] = t1r - SGN * t3i;  xi[s0 + 3] = t1i + SGN * t3r;
    }
    if (STORE_REV) {
        int q2 = (u >> 2) + ((u & 3) << 2);
#pragma unroll
        for (int s = 0; s < 16; ++s) {
            int dest = q2 + ((s >> 2) << 4) + ((s & 3) << 6);   // rev4(16u+s)
            int a = base + phys(dest);
            Ar[a] = xr[s]; Ai[a] = xi[s];
        }
    } else {
#pragma unroll
        for (int v = 0; v < 4; ++v) {
            *(float4*)(Ar + a0 + 4 * v) = make_float4(xr[4*v], xr[4*v+1], xr[4*v+2], xr[4*v+3]);
            *(float4*)(Ai + a0 + 4 * v) = make_float4(xi[4*v], xi[4*v+1], xi[4*v+2], xi[4*v+3]);
        }
    }
}

// Wc4[i][jc][f] = float4(Hc[f][i][2jc].re,.im, Hc[f][i][2jc+1].re,.im),
// f = 0..128 (pad 132), Hc = conj(FFT_256(W[i,j,:])). 270 KB in d_ws.
__global__ __launch_bounds__(256) void wfft_kernel(const float* __restrict__ W,
                                                   float* __restrict__ Wc4)
{
    __shared__ float wblk[256];
    __shared__ float tabc[256], tabs[256];
    int t   = threadIdx.x;                 // t = frequency f
    int blk = blockIdx.x;                  // blk = i*16 + j
    wblk[t] = W[blk * 256 + t];
    float s, c;
    __sincosf((float)t * (TWO_PI / 256.f), &s, &c);
    tabc[t] = c; tabs[t] = s;
    __syncthreads();
    if (t <= 128) {
        float ar = 0.f, ai = 0.f;
        for (int cc = 0; cc < 256; ++cc) {
            int idx = (t * cc) & 255;
            float wv = wblk[cc];
            ar = fmaf(wv, tabc[idx], ar);
            ai = fmaf(wv, tabs[idx], ai);
        }
        int i = blk >> 4, j = blk & 15;
        int flat = ((i * 8 + (j >> 1)) * 132 + t) * 4 + ((j & 1) << 1);
        Wc4[flat]     = ar;
        Wc4[flat + 1] = ai;
    }
}

__global__ __launch_bounds__(256, 2)
void bc_kernel(const float* __restrict__ x,
               const float* __restrict__ d,
               const float* __restrict__ bias,
               const float* __restrict__ Wc4,
               float* __restrict__ out)
{
    __shared__ float Ar[16 * RS], Ai[16 * RS];   // 38 KiB total -> 4 blocks/CU
    int t  = threadIdx.x;
    int b0 = blockIdx.x * 2;               // rows b0 (real part), b0+1 (imag part)
    int w = t >> 6, l = t & 63;
    int u = t & 15;
    int base = (t >> 4) * RS;              // region = 4w + (l>>4), wave-owned

    // ---- load: z_j = x0_j*d + i*x1_j*d, wave w loads its own regions 4w..4w+3
    const float4* d4 = (const float4*)d;
    const float4* x40 = (const float4*)(x + (size_t)b0 * 4096);
    const float4* x41 = (const float4*)(x + (size_t)(b0 + 1) * 4096);
#pragma unroll
    for (int it = 0; it < 4; ++it) {
        int idx = 256 * w + 64 * it + l;
        float4 dv = d4[idx];
        float4 v0 = x40[idx];
        float4 v1 = x41[idx];
        int a = (4 * w + it) * RS + 4 * l + ((l >> 3) << 2);   // phys(4l)
        *(float4*)(Ar + a) = make_float4(v0.x * dv.x, v0.y * dv.y, v0.z * dv.z, v0.w * dv.w);
        *(float4*)(Ai + a) = make_float4(v1.x * dv.x, v1.y * dv.y, v1.z * dv.z, v1.w * dv.w);
    }
    // no barrier: regions are wave-private, DS ops in-order within a wave

    pair1<1>(Ar, Ai, base, u);
    pair2<1, true>(Ar, Ai, base, u);           // scatter -> natural-order spectrum
    __syncthreads();                           // BAR 1: matmul reads cross-wave

    // ---- frequency matmul with unpack/repack: f = t&127, i-half = t>>7;
    //      f=128 handled by lanes t=64..79 AFTER BAR2 (phys(128) column is
    //      neither written nor read by any repack thread -> no reg preload).
    {
        int f  = t & 127;
        int pf = phys(f);
        int pc = phys((256 - f) & 255);
        float zr[16], zi[16], z2r[16], z2i[16];
#pragma unroll
        for (int j = 0; j < 16; ++j) {
            zr[j]  = Ar[j * RS + pf];  zi[j]  = Ai[j * RS + pf];
            z2r[j] = Ar[j * RS + pc];  z2i[j] = Ai[j * RS + pc];
        }
        __syncthreads();                       // BAR 2: all reads before writes

        // unpack in place (2x convention; folded into final 1/512 scale):
        // X0 = Z(f)+conj(Z(-f)), X1 = -i*(Z(f)-conj(Z(-f)))
#pragma unroll
        for (int j = 0; j < 16; ++j) {
            float a = zr[j], b = zi[j], c = z2r[j], dd = z2i[j];
            zr[j]  = a + c;    // X0r
            zi[j]  = b - dd;   // X0i
            z2r[j] = b + dd;   // X1r
            z2i[j] = c - a;    // X1i
        }
        const float4* wb = (const float4*)Wc4;
        int ib = (t >> 7) * 8;
#pragma unroll
        for (int io = 0; io < 8; ++io) {
            int i = ib + io;
            float yr0 = 0.f, yi0 = 0.f, yr1 = 0.f, yi1 = 0.f;
#pragma unroll
            for (int jc = 0; jc < 8; ++jc) {
                float4 wv = wb[(i * 8 + jc) * 132 + f];
                int j0 = 2 * jc;
                yr0 = fmaf(zr[j0], wv.x, yr0);  yr0 = fmaf(-zi[j0], wv.y, yr0);
                yi0 = fmaf(zr[j0], wv.y, yi0);  yi0 = fmaf(zi[j0], wv.x, yi0);
                yr1 = fmaf(z2r[j0], wv.x, yr1); yr1 = fmaf(-z2i[j0], wv.y, yr1);
                yi1 = fmaf(z2r[j0], wv.y, yi1); yi1 = fmaf(z2i[j0], wv.x, yi1);
                yr0 = fmaf(zr[j0+1], wv.z, yr0);  yr0 = fmaf(-zi[j0+1], wv.w, yr0);
                yi0 = fmaf(zr[j0+1], wv.w, yi0);  yi0 = fmaf(zi[j0+1], wv.z, yi0);
                yr1 = fmaf(z2r[j0+1], wv.z, yr1); yr1 = fmaf(-z2i[j0+1], wv.w, yr1);
                yi1 = fmaf(z2r[j0+1], wv.w, yi1); yi1 = fmaf(z2i[j0+1], wv.z, yi1);
            }
            // repack: W(f) = Y0 + i*Y1;  W(256-f) = conj(Y0) + i*conj(Y1)
            Ar[i * RS + pf] = yr0 - yi1;
            Ai[i * RS + pf] = yi0 + yr1;
            if (f >= 1) {
                Ar[i * RS + pc] = yr0 + yi1;
                Ai[i * RS + pc] = yr1 - yi0;
            }
        }
        if (t >= 64 && t < 80) {               // f=128: read+write phys(128) col,
            int i = t - 64;                    // untouched by any other thread here
            int p8 = phys(128);
            float yr0 = 0.f, yi0 = 0.f, yr1 = 0.f, yi1 = 0.f;
#pragma unroll
            for (int jc = 0; jc < 8; ++jc) {
                float4 wv = wb[(i * 8 + jc) * 132 + 128];
                int j0 = 2 * jc;
                float a0r = Ar[j0 * RS + p8],       a0i = Ai[j0 * RS + p8];
                float a1r = Ar[(j0 + 1) * RS + p8], a1i = Ai[(j0 + 1) * RS + p8];
                // X0 = 2*Re(Z), X1 = 2*Im(Z) at f=128 (factor 2 applied at store)
                yr0 = fmaf(a0r, wv.x, yr0);   yi0 = fmaf(a0r, wv.y, yi0);
                yr1 = fmaf(a0i, wv.x, yr1);   yi1 = fmaf(a0i, wv.y, yi1);
                yr0 = fmaf(a1r, wv.z, yr0);   yi0 = fmaf(a1r, wv.w, yi0);
                yr1 = fmaf(a1i, wv.z, yr1);   yi1 = fmaf(a1i, wv.w, yi1);
            }
            Ar[i * RS + p8] = 2.f * (yr0 - yi1);
            Ai[i * RS + p8] = 2.f * (yi0 + yr1);
        }
    }
    __syncthreads();                           // BAR 3

    pair1<-1>(Ar, Ai, base, u);
    pair2<-1, false>(Ar, Ai, base, u);         // full complex out, contiguous store
    // no barrier: gather below reads own-wave regions only

    // ---- store: gather rev4 positions; Re -> row b0, Im -> row b0+1
    const float4* b4 = (const float4*)bias;
    float* o0 = out + (size_t)b0 * 4096;
    float* o1 = out + (size_t)(b0 + 1) * 4096;
    int dbase = ((l >> 4) & 3) + (((l >> 2) & 3) << 2) + ((l & 3) << 4);
#pragma unroll
    for (int it = 0; it < 4; ++it) {
        int idx = 256 * w + 64 * it + l;
        int rb  = (4 * w + it) * RS;
        float v0[4], v1[4];
#pragma unroll
        for (int e = 0; e < 4; ++e) {
            int a = rb + phys(dbase + (e << 6));   // rev4(4l+e)
            v0[e] = Ar[a];
            v1[e] = Ai[a];
        }
        float4 bv = b4[idx];
        float4 ov0, ov1;
        ov0.x = v0[0] * (1.f / 512.f) + bv.x;
        ov0.y = v0[1] * (1.f / 512.f) + bv.y;
        ov0.z = v0[2] * (1.f / 512.f) + bv.z;
        ov0.w = v0[3] * (1.f / 512.f) + bv.w;
        ov1.x = v1[0] * (1.f / 512.f) + bv.x;
        ov1.y = v1[1] * (1.f / 512.f) + bv.y;
        ov1.z = v1[2] * (1.f / 512.f) + bv.z;
        ov1.w = v1[3] * (1.f / 512.f) + bv.w;
        ((float4*)o0)[idx] = ov0;
        ((float4*)o1)[idx] = ov1;
    }
}

extern "C" void kernel_launch(void* const* d_in, const int* in_sizes, int n_in,
                              void* d_out, int out_size, void* d_ws, size_t ws_size,
                              hipStream_t stream)
{
    const float* x    = (const float*)d_in[0];   // (8192, 4096)
    const float* W    = (const float*)d_in[1];   // (16, 16, 256)
    const float* d    = (const float*)d_in[2];   // (4096,)
    const float* bias = (const float*)d_in[3];   // (4096,)
    float* out = (float*)d_out;
    float* Wc4 = (float*)d_ws;                   // [16][8][132] float4 = 270 KB

    wfft_kernel<<<256, 256, 0, stream>>>(W, Wc4);
    bc_kernel<<<4096, 256, 0, stream>>>(x, d, bias, Wc4, out);
}

// Round 10
// 293.988 us; speedup vs baseline: 1.2902x; 1.0036x over previous
//
#include <hip/hip_runtime.h>

// Block-circulant matmul via FFT, round 9 (resubmit — GPU acquisition timed
// out, kernel never measured): occupancy + barrier reduction.
// Round 8 counters: spills eliminated (WRITE=131MB compulsory) but dur flat at
// 158us with VALUBusy 30%, HBM 16%, conflicts 4%, Occupancy 32% -> the kernel
// is latency/overlap-bound, not resource-bound. Fixes:
//  (1) RS 304 -> 256 with XOR-swizzled LDS addressing:
//      addr = r*256 + (a ^ ((a>>3)&28) ^ ((r&1)<<4))
//      bijective per region, keeps float4 runs contiguous (bits 0-1 intact),
//      region parity preserves pair1's 2-way bank behavior. LDS 38912->32768B
//      -> exactly 5 blocks/CU (was 4): +25% resident waves for latency hiding.
//  (2) Same-wave f-pairing: f = 32*wave + (lane>>1), ihalf = lane&1. The
//      column pair {f, 256-f} is read and written ONLY by two lanes of the
//      same wave; wave DS ops are in-order -> BAR2 (read-before-overwrite)
//      deleted. 3 barriers -> 2. Matmul LDS reads become conflict-free
//      (32 banks x pair-broadcast).
// Algorithm unchanged: rows packed z = x0*d + i*x1*d, 16 complex FFT-256 per
// block, unpack X0/X1 via conj symmetry, repack W = Y0 + i*Y1, one complex
// iFFT, Re->row0 / Im->row1. f=128 column owned by wave-1 lanes 0..15 (read+
// write after their main f work; col 128 untouched by any other thread).

#define TWO_PI 6.283185307179586f

// XOR-swizzled LDS address: region r in 0..15, offset a in 0..255.
__device__ __forceinline__ int swz(int r, int a)
{
    return (r << 8) + (a ^ ((a >> 3) & 28) ^ ((r & 1) << 4));
}

// (vr,vi) *= e^{-i*SGN*alpha}, where (c,s) = (cos alpha, sin alpha)
template<int SGN>
__device__ __forceinline__ void twmul(float& vr, float& vi, float c, float s)
{
    float r = vr * c + SGN * (vi * s);
    float i = vi * c - SGN * (vr * s);
    vr = r; vi = i;
}

// Pair 1 = DIF stages D=64 and D=16, th = 2*pi*u/256.
// Elements: position u + 16m + 64k <-> register s = m + 4k. Complex in/out.
template<int SGN>
__device__ __forceinline__ void pair1(float* __restrict__ Ar, float* __restrict__ Ai,
                                      int reg, int u)
{
    float xr[16], xi[16];
#pragma unroll
    for (int s = 0; s < 16; ++s) {
        int a = swz(reg, u + 16 * s);
        xr[s] = Ar[a];
        xi[s] = Ai[a];
    }
    float su, cu;
    __sincosf((float)u * (TWO_PI / 256.f), &su, &cu);
    const float CM[4] = {1.f, 0.92387953f, 0.70710678f, 0.38268343f};
    const float SM[4] = {0.f, 0.38268343f, 0.70710678f, 0.92387953f};
    float c1[4], s1[4], c2[4], s2[4], c3[4], s3[4];
#pragma unroll
    for (int m = 0; m < 4; ++m) {
        c1[m] = cu * CM[m] - su * SM[m];
        s1[m] = su * CM[m] + cu * SM[m];
        c2[m] = c1[m] * c1[m] - s1[m] * s1[m];
        s2[m] = 2.f * c1[m] * s1[m];
        c3[m] = c2[m] * c1[m] - s2[m] * s1[m];
        s3[m] = s2[m] * c1[m] + c2[m] * s1[m];
    }
    // stage A (D=64): A_k = x[m+4k]
#pragma unroll
    for (int m = 0; m < 4; ++m) {
        float t0r = xr[m] + xr[m + 8],       t0i = xi[m] + xi[m + 8];
        float t1r = xr[m] - xr[m + 8],       t1i = xi[m] - xi[m + 8];
        float t2r = xr[m + 4] + xr[m + 12],  t2i = xi[m + 4] + xi[m + 12];
        float t3r = xr[m + 4] - xr[m + 12],  t3i = xi[m + 4] - xi[m + 12];
        xr[m] = t0r + t2r;  xi[m] = t0i + t2i;
        float v1r = t1r + SGN * t3i, v1i = t1i - SGN * t3r;
        float v2r = t0r - t2r,       v2i = t0i - t2i;
        float v3r = t1r - SGN * t3i, v3i = t1i + SGN * t3r;
        twmul<SGN>(v1r, v1i, c1[m], s1[m]);
        twmul<SGN>(v2r, v2i, c2[m], s2[m]);
        twmul<SGN>(v3r, v3i, c3[m], s3[m]);
        xr[m + 4]  = v1r; xi[m + 4]  = v1i;
        xr[m + 8]  = v2r; xi[m + 8]  = v2i;
        xr[m + 12] = v3r; xi[m + 12] = v3i;
    }
    // stage B (D=16): A_m = x[4k+m], twiddle angles 4th, 8th, 12th
    float cb1 = cu * cu - su * su, sb1 = 2.f * cu * su;                  // 2th
    { float c = cb1, s = sb1; cb1 = c * c - s * s; sb1 = 2.f * c * s; }  // 4th
    float cb2 = cb1 * cb1 - sb1 * sb1, sb2 = 2.f * cb1 * sb1;            // 8th
    float cb3 = cb2 * cb1 - sb2 * sb1, sb3 = sb2 * cb1 + cb2 * sb1;      // 12th
#pragma unroll
    for (int k = 0; k < 4; ++k) {
        int s0 = 4 * k;
        float t0r = xr[s0] + xr[s0 + 2],     t0i = xi[s0] + xi[s0 + 2];
        float t1r = xr[s0] - xr[s0 + 2],     t1i = xi[s0] - xi[s0 + 2];
        float t2r = xr[s0 + 1] + xr[s0 + 3], t2i = xi[s0 + 1] + xi[s0 + 3];
        float t3r = xr[s0 + 1] - xr[s0 + 3], t3i = xi[s0 + 1] - xi[s0 + 3];
        xr[s0] = t0r + t2r;  xi[s0] = t0i + t2i;
        float v1r = t1r + SGN * t3i, v1i = t1i - SGN * t3r;
        float v2r = t0r - t2r,       v2i = t0i - t2i;
        float v3r = t1r - SGN * t3i, v3i = t1i + SGN * t3r;
        twmul<SGN>(v1r, v1i, cb1, sb1);
        twmul<SGN>(v2r, v2i, cb2, sb2);
        twmul<SGN>(v3r, v3i, cb3, sb3);
        xr[s0 + 1] = v1r; xi[s0 + 1] = v1i;
        xr[s0 + 2] = v2r; xi[s0 + 2] = v2i;
        xr[s0 + 3] = v3r; xi[s0 + 3] = v3i;
    }
#pragma unroll
    for (int s = 0; s < 16; ++s) {
        int a = swz(reg, u + 16 * s);
        Ar[a] = xr[s]; Ai[a] = xi[s];
    }
}

// Pair 2 = DIF stages D=4 (compile-time twiddles) and D=1.
// Elements: position 16u + s (float4 LDS I/O, swizzle preserves 16B runs).
// STORE_REV: scatter outputs to rev4(position) (natural-order spectrum).
template<int SGN, bool STORE_REV>
__device__ __forceinline__ void pair2(float* __restrict__ Ar, float* __restrict__ Ai,
                                      int reg, int u)
{
    float xr[16], xi[16];
#pragma unroll
    for (int v = 0; v < 4; ++v) {
        int a = swz(reg, 16 * u + 4 * v);
        float4 vr = *(const float4*)(Ar + a);
        float4 vi = *(const float4*)(Ai + a);
        xr[4 * v] = vr.x; xr[4 * v + 1] = vr.y; xr[4 * v + 2] = vr.z; xr[4 * v + 3] = vr.w;
        xi[4 * v] = vi.x; xi[4 * v + 1] = vi.y; xi[4 * v + 2] = vi.z; xi[4 * v + 3] = vi.w;
    }
    // stage C (D=4): A_m = x[q+4m], twiddle (c,s) of pi*q*r/8
    const float CQ[4][4] = {
        {1.f, 1.f, 1.f, 1.f},
        {1.f, 0.92387953f, 0.70710678f, 0.38268343f},
        {1.f, 0.70710678f, 0.f, -0.70710678f},
        {1.f, 0.38268343f, -0.70710678f, -0.92387953f}};
    const float SQ[4][4] = {
        {0.f, 0.f, 0.f, 0.f},
        {0.f, 0.38268343f, 0.70710678f, 0.92387953f},
        {0.f, 0.70710678f, 1.f, 0.70710678f},
        {0.f, 0.92387953f, 0.70710678f, -0.38268343f}};
#pragma unroll
    for (int q = 0; q < 4; ++q) {
        float t0r = xr[q] + xr[q + 8],       t0i = xi[q] + xi[q + 8];
        float t1r = xr[q] - xr[q + 8],       t1i = xi[q] - xi[q + 8];
        float t2r = xr[q + 4] + xr[q + 12],  t2i = xi[q + 4] + xi[q + 12];
        float t3r = xr[q + 4] - xr[q + 12],  t3i = xi[q + 4] - xi[q + 12];
        xr[q] = t0r + t2r;  xi[q] = t0i + t2i;
        float v1r = t1r + SGN * t3i, v1i = t1i - SGN * t3r;
        float v2r = t0r - t2r,       v2i = t0i - t2i;
        float v3r = t1r - SGN * t3i, v3i = t1i + SGN * t3r;
        twmul<SGN>(v1r, v1i, CQ[q][1], SQ[q][1]);
        twmul<SGN>(v2r, v2i, CQ[q][2], SQ[q][2]);
        twmul<SGN>(v3r, v3i, CQ[q][3], SQ[q][3]);
        xr[q + 4]  = v1r; xi[q + 4]  = v1i;
        xr[q + 8]  = v2r; xi[q + 8]  = v2i;
        xr[q + 12] = v3r; xi[q + 12] = v3i;
    }
    // stage D (D=1): contiguous quads, no twiddle
#pragma unroll
    for (int g = 0; g < 4; ++g) {
        int s0 = 4 * g;
        float t0r = xr[s0] + xr[s0 + 2],     t1r = xr[s0] - xr[s0 + 2];
        float t2r = xr[s0 + 1] + xr[s0 + 3], t3r = xr[s0 + 1] - xr[s0 + 3];
        float t0i = xi[s0] + xi[s0 + 2],     t1i = xi[s0] - xi[s0 + 2];
        float t2i = xi[s0 + 1] + xi[s0 + 3], t3i = xi[s0 + 1] - xi[s0 + 3];
        xr[s0]     = t0r + t2r;  xi[s0]     = t0i + t2i;
        xr[s0 + 1] = t1r + SGN * t3i;  xi[s0 + 1] = t1i - SGN * t3r;
        xr[s0 + 2] = t0r - t2r;        xi[s0 + 2] = t0i - t2i;
        xr[s0 + 3] = t1r - SGN * t3i;  xi[s0 + 3] = t1i + SGN * t3r;
    }
    if (STORE_REV) {
        int q2 = (u >> 2) + ((u & 3) << 2);
#pragma unroll
        for (int s = 0; s < 16; ++s) {
            int dest = q2 + ((s >> 2) << 4) + ((s & 3) << 6);   // rev4(16u+s)
            int a = swz(reg, dest);
            Ar[a] = xr[s]; Ai[a] = xi[s];
        }
    } else {
#pragma unroll
        for (int v = 0; v < 4; ++v) {
            int a = swz(reg, 16 * u + 4 * v);
            *(float4*)(Ar + a) = make_float4(xr[4*v], xr[4*v+1], xr[4*v+2], xr[4*v+3]);
            *(float4*)(Ai + a) = make_float4(xi[4*v], xi[4*v+1], xi[4*v+2], xi[4*v+3]);
        }
    }
}

// Wc4[i][jc][f] = float4(Hc[f][i][2jc].re,.im, Hc[f][i][2jc+1].re,.im),
// f = 0..128 (pad 132), Hc = conj(FFT_256(W[i,j,:])). 270 KB in d_ws.
__global__ __launch_bounds__(256) void wfft_kernel(const float* __restrict__ W,
                                                   float* __restrict__ Wc4)
{
    __shared__ float wblk[256];
    __shared__ float tabc[256], tabs[256];
    int t   = threadIdx.x;                 // t = frequency f
    int blk = blockIdx.x;                  // blk = i*16 + j
    wblk[t] = W[blk * 256 + t];
    float s, c;
    __sincosf((float)t * (TWO_PI / 256.f), &s, &c);
    tabc[t] = c; tabs[t] = s;
    __syncthreads();
    if (t <= 128) {
        float ar = 0.f, ai = 0.f;
        for (int cc = 0; cc < 256; ++cc) {
            int idx = (t * cc) & 255;
            float wv = wblk[cc];
            ar = fmaf(wv, tabc[idx], ar);
            ai = fmaf(wv, tabs[idx], ai);
        }
        int i = blk >> 4, j = blk & 15;
        int flat = ((i * 8 + (j >> 1)) * 132 + t) * 4 + ((j & 1) << 1);
        Wc4[flat]     = ar;
        Wc4[flat + 1] = ai;
    }
}

__global__ __launch_bounds__(256, 2)
void bc_kernel(const float* __restrict__ x,
               const float* __restrict__ d,
               const float* __restrict__ bias,
               const float* __restrict__ Wc4,
               float* __restrict__ out)
{
    __shared__ float Ar[16 * 256], Ai[16 * 256];   // 32 KiB total -> 5 blocks/CU
    int t  = threadIdx.x;
    int b0 = blockIdx.x * 2;               // rows b0 (real part), b0+1 (imag part)
    int w = t >> 6, l = t & 63;
    int u = t & 15;
    int reg = t >> 4;                      // region = 4w + (l>>4), wave-owned

    // ---- load: z_j = x0_j*d + i*x1_j*d, wave w loads its own regions 4w..4w+3
    const float4* d4 = (const float4*)d;
    const float4* x40 = (const float4*)(x + (size_t)b0 * 4096);
    const float4* x41 = (const float4*)(x + (size_t)(b0 + 1) * 4096);
#pragma unroll
    for (int it = 0; it < 4; ++it) {
        int idx = 256 * w + 64 * it + l;
        float4 dv = d4[idx];
        float4 v0 = x40[idx];
        float4 v1 = x41[idx];
        int a = swz(4 * w + it, 4 * l);
        *(float4*)(Ar + a) = make_float4(v0.x * dv.x, v0.y * dv.y, v0.z * dv.z, v0.w * dv.w);
        *(float4*)(Ai + a) = make_float4(v1.x * dv.x, v1.y * dv.y, v1.z * dv.z, v1.w * dv.w);
    }
    // no barrier: regions are wave-private, DS ops in-order within a wave

    pair1<1>(Ar, Ai, reg, u);
    pair2<1, true>(Ar, Ai, reg, u);            // scatter -> natural-order spectrum
    __syncthreads();                           // BAR 1: matmul reads cross-wave

    // ---- frequency matmul with unpack/repack.
    // f = 32*wave + (lane>>1), ihalf = lane&1: the column pair {f, 256-f} is
    // read AND written only by two lanes of the SAME wave -> no barrier needed
    // between the reads and the writes (wave DS ops are in-order).
    {
        int f  = (w << 5) + (l >> 1);          // 0..127
        int ih = l & 1;                        // i-half
        int cA = f;
        int cB = (256 - f) & 255;
        float zr[16], zi[16], z2r[16], z2i[16];
#pragma unroll
        for (int j = 0; j < 16; ++j) {
            zr[j]  = Ar[swz(j, cA)];  zi[j]  = Ai[swz(j, cA)];
            z2r[j] = Ar[swz(j, cB)];  z2i[j] = Ai[swz(j, cB)];
        }
        // unpack in place (2x convention; folded into final 1/512 scale):
        // X0 = Z(f)+conj(Z(-f)), X1 = -i*(Z(f)-conj(Z(-f)))
#pragma unroll
        for (int j = 0; j < 16; ++j) {
            float a = zr[j], b = zi[j], c = z2r[j], dd = z2i[j];
            zr[j]  = a + c;    // X0r
            zi[j]  = b - dd;   // X0i
            z2r[j] = b + dd;   // X1r
            z2i[j] = c - a;    // X1i
        }
        const float4* wb = (const float4*)Wc4;
        int ib = ih * 8;
#pragma unroll
        for (int io = 0; io < 8; ++io) {
            int i = ib + io;
            float yr0 = 0.f, yi0 = 0.f, yr1 = 0.f, yi1 = 0.f;
#pragma unroll
            for (int jc = 0; jc < 8; ++jc) {
                float4 wv = wb[(i * 8 + jc) * 132 + f];
                int j0 = 2 * jc;
                yr0 = fmaf(zr[j0], wv.x, yr0);  yr0 = fmaf(-zi[j0], wv.y, yr0);
                yi0 = fmaf(zr[j0], wv.y, yi0);  yi0 = fmaf(zi[j0], wv.x, yi0);
                yr1 = fmaf(z2r[j0], wv.x, yr1); yr1 = fmaf(-z2i[j0], wv.y, yr1);
                yi1 = fmaf(z2r[j0], wv.y, yi1); yi1 = fmaf(z2i[j0], wv.x, yi1);
                yr0 = fmaf(zr[j0+1], wv.z, yr0);  yr0 = fmaf(-zi[j0+1], wv.w, yr0);
                yi0 = fmaf(zr[j0+1], wv.w, yi0);  yi0 = fmaf(zi[j0+1], wv.z, yi0);
                yr1 = fmaf(z2r[j0+1], wv.z, yr1); yr1 = fmaf(-z2i[j0+1], wv.w, yr1);
                yi1 = fmaf(z2r[j0+1], wv.w, yi1); yi1 = fmaf(z2i[j0+1], wv.z, yi1);
            }
            // repack: W(f) = Y0 + i*Y1;  W(256-f) = conj(Y0) + i*conj(Y1)
            Ar[swz(i, cA)] = yr0 - yi1;
            Ai[swz(i, cA)] = yi0 + yr1;
            if (f >= 1) {
                Ar[swz(i, cB)] = yr0 + yi1;
                Ai[swz(i, cB)] = yr1 - yi0;
            }
        }
        if (t >= 64 && t < 80) {               // f=128: col 128 is read+written
            int i = t - 64;                    // ONLY by these 16 same-wave lanes
            float yr0 = 0.f, yi0 = 0.f, yr1 = 0.f, yi1 = 0.f;
#pragma unroll
            for (int jc = 0; jc < 8; ++jc) {
                float4 wv = wb[(i * 8 + jc) * 132 + 128];
                int j0 = 2 * jc;
                float a0r = Ar[swz(j0, 128)],     a0i = Ai[swz(j0, 128)];
                float a1r = Ar[swz(j0 + 1, 128)], a1i = Ai[swz(j0 + 1, 128)];
                // X0 = 2*Re(Z), X1 = 2*Im(Z) at f=128 (factor 2 applied at store)
                yr0 = fmaf(a0r, wv.x, yr0);   yi0 = fmaf(a0r, wv.y, yi0);
                yr1 = fmaf(a0i, wv.x, yr1);   yi1 = fmaf(a0i, wv.y, yi1);
                yr0 = fmaf(a1r, wv.z, yr0);   yi0 = fmaf(a1r, wv.w, yi0);
                yr1 = fmaf(a1i, wv.z, yr1);   yi1 = fmaf(a1i, wv.w, yi1);
            }
            Ar[swz(i, 128)] = 2.f * (yr0 - yi1);
            Ai[swz(i, 128)] = 2.f * (yi0 + yr1);
        }
    }
    __syncthreads();                           // BAR 2: inverse reads cross-wave

    pair1<-1>(Ar, Ai, reg, u);
    pair2<-1, false>(Ar, Ai, reg, u);          // full complex out, contiguous store
    // no barrier: gather below reads own-wave regions only

    // ---- store: gather rev4 positions; Re -> row b0, Im -> row b0+1
    const float4* b4 = (const float4*)bias;
    float* o0 = out + (size_t)b0 * 4096;
    float* o1 = out + (size_t)(b0 + 1) * 4096;
    int dbase = ((l >> 4) & 3) + (((l >> 2) & 3) << 2) + ((l & 3) << 4);
#pragma unroll
    for (int it = 0; it < 4; ++it) {
        int idx = 256 * w + 64 * it + l;
        int rg  = 4 * w + it;
        float v0[4], v1[4];
#pragma unroll
        for (int e = 0; e < 4; ++e) {
            int a = swz(rg, dbase + (e << 6));   // rev4(4l+e)
            v0[e] = Ar[a];
            v1[e] = Ai[a];
        }
        float4 bv = b4[idx];
        float4 ov0, ov1;
        ov0.x = v0[0] * (1.f / 512.f) + bv.x;
        ov0.y = v0[1] * (1.f / 512.f) + bv.y;
        ov0.z = v0[2] * (1.f / 512.f) + bv.z;
        ov0.w = v0[3] * (1.f / 512.f) + bv.w;
        ov1.x = v1[0] * (1.f / 512.f) + bv.x;
        ov1.y = v1[1] * (1.f / 512.f) + bv.y;
        ov1.z = v1[2] * (1.f / 512.f) + bv.z;
        ov1.w = v1[3] * (1.f / 512.f) + bv.w;
        ((float4*)o0)[idx] = ov0;
        ((float4*)o1)[idx] = ov1;
    }
}

extern "C" void kernel_launch(void* const* d_in, const int* in_sizes, int n_in,
                              void* d_out, int out_size, void* d_ws, size_t ws_size,
                              hipStream_t stream)
{
    const float* x    = (const float*)d_in[0];   // (8192, 4096)
    const float* W    = (const float*)d_in[1];   // (16, 16, 256)
    const float* d    = (const float*)d_in[2];   // (4096,)
    const float* bias = (const float*)d_in[3];   // (4096,)
    float* out = (float*)d_out;
    float* Wc4 = (float*)d_ws;                   // [16][8][132] float4 = 270 KB

    wfft_kernel<<<256, 256, 0, stream>>>(W, Wc4);
    bc_kernel<<<4096, 256, 0, stream>>>(x, d, bias, Wc4, out);
}

// Round 13
// 293.817 us; speedup vs baseline: 1.2910x; 1.0006x over previous
//
#include <hip/hip_runtime.h>

// Block-circulant matmul via FFT, round 10 (3rd submit — two consecutive GPU
// acquisition timeouts; kernel never measured): unpack-free frequency matmul.
// KEY REALIZATION (algebra, verified): the round-6..9 unpack/repack was
// unnecessary. By linearity, ifft(Hc * FFT(x0*d + i*x1*d)) = y0 + i*y1
// directly - both packed rows share the same real-kernel spectrum Hc, so
// Y_packed[i][c] = sum_j Hc[i][j][c] * Z[j][c] for ALL 256 columns, using
// Hc's conjugate symmetry Hc(c) = conj(Hc(256-c)) for c>128. The conj is
// applied sign-free: zi *= sgn at load, yi *= sgn at store (32 VALU total).
// Round 9 counters (VGPR 100 -> 4 waves/SIMD cap; occupancy stuck 22%): the
// matmul live set must shrink before occupancy can rise. New mapping:
// 1 thread = 1 column c = t, all 16 i outputs. Effects:
//  - live set: zr/zi[16] = 32 regs (was 64) -> VGPR ~72-84 expected
//  - matmul LDS reads halve (32 b32); conflict-free under swz
//  - unpack/repack/f=128 special case deleted (~150 VALU/thread)
//  - column c read+written by ONE thread -> still no barrier in matmul
// Structure: load z -> fwd FFT (pair1+pair2, wave-private regions) -> BAR1 ->
// matmul (per-column) -> BAR2 -> inv FFT -> store Re->row0, Im->row1.
// 2 barriers/block. LDS 32 KiB (swz XOR layout). Scale 1/256 (no 2x).

#define TWO_PI 6.283185307179586f

// XOR-swizzled LDS address: region r in 0..15, offset a in 0..255.
__device__ __forceinline__ int swz(int r, int a)
{
    return (r << 8) + (a ^ ((a >> 3) & 28) ^ ((r & 1) << 4));
}

// (vr,vi) *= e^{-i*SGN*alpha}, where (c,s) = (cos alpha, sin alpha)
template<int SGN>
__device__ __forceinline__ void twmul(float& vr, float& vi, float c, float s)
{
    float r = vr * c + SGN * (vi * s);
    float i = vi * c - SGN * (vr * s);
    vr = r; vi = i;
}

// Pair 1 = DIF stages D=64 and D=16, th = 2*pi*u/256.
// Elements: position u + 16m + 64k <-> register s = m + 4k. Complex in/out.
template<int SGN>
__device__ __forceinline__ void pair1(float* __restrict__ Ar, float* __restrict__ Ai,
                                      int reg, int u)
{
    float xr[16], xi[16];
#pragma unroll
    for (int s = 0; s < 16; ++s) {
        int a = swz(reg, u + 16 * s);
        xr[s] = Ar[a];
        xi[s] = Ai[a];
    }
    float su, cu;
    __sincosf((float)u * (TWO_PI / 256.f), &su, &cu);
    const float CM[4] = {1.f, 0.92387953f, 0.70710678f, 0.38268343f};
    const float SM[4] = {0.f, 0.38268343f, 0.70710678f, 0.92387953f};
    float c1[4], s1[4], c2[4], s2[4], c3[4], s3[4];
#pragma unroll
    for (int m = 0; m < 4; ++m) {
        c1[m] = cu * CM[m] - su * SM[m];
        s1[m] = su * CM[m] + cu * SM[m];
        c2[m] = c1[m] * c1[m] - s1[m] * s1[m];
        s2[m] = 2.f * c1[m] * s1[m];
        c3[m] = c2[m] * c1[m] - s2[m] * s1[m];
        s3[m] = s2[m] * c1[m] + c2[m] * s1[m];
    }
    // stage A (D=64): A_k = x[m+4k]
#pragma unroll
    for (int m = 0; m < 4; ++m) {
        float t0r = xr[m] + xr[m + 8],       t0i = xi[m] + xi[m + 8];
        float t1r = xr[m] - xr[m + 8],       t1i = xi[m] - xi[m + 8];
        float t2r = xr[m + 4] + xr[m + 12],  t2i = xi[m + 4] + xi[m + 12];
        float t3r = xr[m + 4] - xr[m + 12],  t3i = xi[m + 4] - xi[m + 12];
        xr[m] = t0r + t2r;  xi[m] = t0i + t2i;
        float v1r = t1r + SGN * t3i, v1i = t1i - SGN * t3r;
        float v2r = t0r - t2r,       v2i = t0i - t2i;
        float v3r = t1r - SGN * t3i, v3i = t1i + SGN * t3r;
        twmul<SGN>(v1r, v1i, c1[m], s1[m]);
        twmul<SGN>(v2r, v2i, c2[m], s2[m]);
        twmul<SGN>(v3r, v3i, c3[m], s3[m]);
        xr[m + 4]  = v1r; xi[m + 4]  = v1i;
        xr[m + 8]  = v2r; xi[m + 8]  = v2i;
        xr[m + 12] = v3r; xi[m + 12] = v3i;
    }
    // stage B (D=16): A_m = x[4k+m], twiddle angles 4th, 8th, 12th
    float cb1 = cu * cu - su * su, sb1 = 2.f * cu * su;                  // 2th
    { float c = cb1, s = sb1; cb1 = c * c - s * s; sb1 = 2.f * c * s; }  // 4th
    float cb2 = cb1 * cb1 - sb1 * sb1, sb2 = 2.f * cb1 * sb1;            // 8th
    float cb3 = cb2 * cb1 - sb2 * sb1, sb3 = sb2 * cb1 + cb2 * sb1;      // 12th
#pragma unroll
    for (int k = 0; k < 4; ++k) {
        int s0 = 4 * k;
        float t0r = xr[s0] + xr[s0 + 2],     t0i = xi[s0] + xi[s0 + 2];
        float t1r = xr[s0] - xr[s0 + 2],     t1i = xi[s0] - xi[s0 + 2];
        float t2r = xr[s0 + 1] + xr[s0 + 3], t2i = xi[s0 + 1] + xi[s0 + 3];
        float t3r = xr[s0 + 1] - xr[s0 + 3], t3i = xi[s0 + 1] - xi[s0 + 3];
        xr[s0] = t0r + t2r;  xi[s0] = t0i + t2i;
        float v1r = t1r + SGN * t3i, v1i = t1i - SGN * t3r;
        float v2r = t0r - t2r,       v2i = t0i - t2i;
        float v3r = t1r - SGN * t3i, v3i = t1i + SGN * t3r;
        twmul<SGN>(v1r, v1i, cb1, sb1);
        twmul<SGN>(v2r, v2i, cb2, sb2);
        twmul<SGN>(v3r, v3i, cb3, sb3);
        xr[s0 + 1] = v1r; xi[s0 + 1] = v1i;
        xr[s0 + 2] = v2r; xi[s0 + 2] = v2i;
        xr[s0 + 3] = v3r; xi[s0 + 3] = v3i;
    }
#pragma unroll
    for (int s = 0; s < 16; ++s) {
        int a = swz(reg, u + 16 * s);
        Ar[a] = xr[s]; Ai[a] = xi[s];
    }
}

// Pair 2 = DIF stages D=4 (compile-time twiddles) and D=1.
// Elements: position 16u + s (float4 LDS I/O, swizzle preserves 16B runs).
// STORE_REV: scatter outputs to rev4(position) (natural-order spectrum).
template<int SGN, bool STORE_REV>
__device__ __forceinline__ void pair2(float* __restrict__ Ar, float* __restrict__ Ai,
                                      int reg, int u)
{
    float xr[16], xi[16];
#pragma unroll
    for (int v = 0; v < 4; ++v) {
        int a = swz(reg, 16 * u + 4 * v);
        float4 vr = *(const float4*)(Ar + a);
        float4 vi = *(const float4*)(Ai + a);
        xr[4 * v] = vr.x; xr[4 * v + 1] = vr.y; xr[4 * v + 2] = vr.z; xr[4 * v + 3] = vr.w;
        xi[4 * v] = vi.x; xi[4 * v + 1] = vi.y; xi[4 * v + 2] = vi.z; xi[4 * v + 3] = vi.w;
    }
    // stage C (D=4): A_m = x[q+4m], twiddle (c,s) of pi*q*r/8
    const float CQ[4][4] = {
        {1.f, 1.f, 1.f, 1.f},
        {1.f, 0.92387953f, 0.70710678f, 0.38268343f},
        {1.f, 0.70710678f, 0.f, -0.70710678f},
        {1.f, 0.38268343f, -0.70710678f, -0.92387953f}};
    const float SQ[4][4] = {
        {0.f, 0.f, 0.f, 0.f},
        {0.f, 0.38268343f, 0.70710678f, 0.92387953f},
        {0.f, 0.70710678f, 1.f, 0.70710678f},
        {0.f, 0.92387953f, 0.70710678f, -0.38268343f}};
#pragma unroll
    for (int q = 0; q < 4; ++q) {
        float t0r = xr[q] + xr[q + 8],       t0i = xi[q] + xi[q + 8];
        float t1r = xr[q] - xr[q + 8],       t1i = xi[q] - xi[q + 8];
        float t2r = xr[q + 4] + xr[q + 12],  t2i = xi[q + 4] + xi[q + 12];
        float t3r = xr[q + 4] - xr[q + 12],  t3i = xi[q + 4] - xi[q + 12];
        xr[q] = t0r + t2r;  xi[q] = t0i + t2i;
        float v1r = t1r + SGN * t3i, v1i = t1i - SGN * t3r;
        float v2r = t0r - t2r,       v2i = t0i - t2i;
        float v3r = t1r - SGN * t3i, v3i = t1i + SGN * t3r;
        twmul<SGN>(v1r, v1i, CQ[q][1], SQ[q][1]);
        twmul<SGN>(v2r, v2i, CQ[q][2], SQ[q][2]);
        twmul<SGN>(v3r, v3i, CQ[q][3], SQ[q][3]);
        xr[q + 4]  = v1r; xi[q + 4]  = v1i;
        xr[q + 8]  = v2r; xi[q + 8]  = v2i;
        xr[q + 12] = v3r; xi[q + 12] = v3i;
    }
    // stage D (D=1): contiguous quads, no twiddle
#pragma unroll
    for (int g = 0; g < 4; ++g) {
        int s0 = 4 * g;
        float t0r = xr[s0] + xr[s0 + 2],     t1r = xr[s0] - xr[s0 + 2];
        float t2r = xr[s0 + 1] + xr[s0 + 3], t3r = xr[s0 + 1] - xr[s0 + 3];
        float t0i = xi[s0] + xi[s0 + 2],     t1i = xi[s0] - xi[s0 + 2];
        float t2i = xi[s0 + 1] + xi[s0 + 3], t3i = xi[s0 + 1] - xi[s0 + 3];
        xr[s0]     = t0r + t2r;  xi[s0]     = t0i + t2i;
        xr[s0 + 1] = t1r + SGN * t3i;  xi[s0 + 1] = t1i - SGN * t3r;
        xr[s0 + 2] = t0r - t2r;        xi[s0 + 2] = t0i - t2i;
        xr[s0 + 3] = t1r - SGN * t3i;  xi[s0 + 3] = t1i + SGN * t3r;
    }
    if (STORE_REV) {
        int q2 = (u >> 2) + ((u & 3) << 2);
#pragma unroll
        for (int s = 0; s < 16; ++s) {
            int dest = q2 + ((s >> 2) << 4) + ((s & 3) << 6);   // rev4(16u+s)
            int a = swz(reg, dest);
            Ar[a] = xr[s]; Ai[a] = xi[s];
        }
    } else {
#pragma unroll
        for (int v = 0; v < 4; ++v) {
            int a = swz(reg, 16 * u + 4 * v);
            *(float4*)(Ar + a) = make_float4(xr[4*v], xr[4*v+1], xr[4*v+2], xr[4*v+3]);
            *(float4*)(Ai + a) = make_float4(xi[4*v], xi[4*v+1], xi[4*v+2], xi[4*v+3]);
        }
    }
}

// Wc4[i][jc][f] = float4(Hc[f][i][2jc].re,.im, Hc[f][i][2jc+1].re,.im),
// f = 0..128 (pad 132), Hc = conj(FFT_256(W[i,j,:])). 270 KB in d_ws.
__global__ __launch_bounds__(256) void wfft_kernel(const float* __restrict__ W,
                                                   float* __restrict__ Wc4)
{
    __shared__ float wblk[256];
    __shared__ float tabc[256], tabs[256];
    int t   = threadIdx.x;                 // t = frequency f
    int blk = blockIdx.x;                  // blk = i*16 + j
    wblk[t] = W[blk * 256 + t];
    float s, c;
    __sincosf((float)t * (TWO_PI / 256.f), &s, &c);
    tabc[t] = c; tabs[t] = s;
    __syncthreads();
    if (t <= 128) {
        float ar = 0.f, ai = 0.f;
        for (int cc = 0; cc < 256; ++cc) {
            int idx = (t * cc) & 255;
            float wv = wblk[cc];
            ar = fmaf(wv, tabc[idx], ar);
            ai = fmaf(wv, tabs[idx], ai);
        }
        int i = blk >> 4, j = blk & 15;
        int flat = ((i * 8 + (j >> 1)) * 132 + t) * 4 + ((j & 1) << 1);
        Wc4[flat]     = ar;
        Wc4[flat + 1] = ai;
    }
}

__global__ __launch_bounds__(256, 2)
void bc_kernel(const float* __restrict__ x,
               const float* __restrict__ d,
               const float* __restrict__ bias,
               const float* __restrict__ Wc4,
               float* __restrict__ out)
{
    __shared__ float Ar[16 * 256], Ai[16 * 256];   // 32 KiB total
    int t  = threadIdx.x;
    int b0 = blockIdx.x * 2;               // rows b0 (real part), b0+1 (imag part)
    int w = t >> 6, l = t & 63;
    int u = t & 15;
    int reg = t >> 4;                      // region = 4w + (l>>4), wave-owned

    // ---- load: z_j = x0_j*d + i*x1_j*d, wave w loads its own regions 4w..4w+3
    const float4* d4 = (const float4*)d;
    const float4* x40 = (const float4*)(x + (size_t)b0 * 4096);
    const float4* x41 = (const float4*)(x + (size_t)(b0 + 1) * 4096);
#pragma unroll
    for (int it = 0; it < 4; ++it) {
        int idx = 256 * w + 64 * it + l;
        float4 dv = d4[idx];
        float4 v0 = x40[idx];
        float4 v1 = x41[idx];
        int a = swz(4 * w + it, 4 * l);
        *(float4*)(Ar + a) = make_float4(v0.x * dv.x, v0.y * dv.y, v0.z * dv.z, v0.w * dv.w);
        *(float4*)(Ai + a) = make_float4(v1.x * dv.x, v1.y * dv.y, v1.z * dv.z, v1.w * dv.w);
    }
    // no barrier: regions are wave-private, DS ops in-order within a wave

    pair1<1>(Ar, Ai, reg, u);
    pair2<1, true>(Ar, Ai, reg, u);            // scatter -> natural-order spectrum
    __syncthreads();                           // BAR 1: matmul reads cross-wave

    // ---- frequency matmul, unpack-free: thread t owns column c = t.
    // Y[i][c] = sum_j Hc[i][j][c] * Z[j][c]; for c>128 use conj symmetry
    // Hc(c) = conj(Hc(256-c)), applied via zi *= sgn at load, yi *= sgn at
    // store (y = conj(sum h*conj(z)) identity). Column c is read AND written
    // only by this thread -> no barrier inside the matmul.
    {
        int c    = t;
        int fidx = (c <= 128) ? c : 256 - c;   // 0..128
        float sgn = (c <= 128) ? 1.f : -1.f;
        float zr[16], zi[16];
#pragma unroll
        for (int j = 0; j < 16; ++j) {
            zr[j] = Ar[swz(j, c)];
            zi[j] = Ai[swz(j, c)] * sgn;
        }
        const float4* wb = (const float4*)Wc4;
#pragma unroll
        for (int i = 0; i < 16; ++i) {
            float yr = 0.f, yi = 0.f;
#pragma unroll
            for (int jc = 0; jc < 8; ++jc) {
                float4 wv = wb[(i * 8 + jc) * 132 + fidx];
                int j0 = 2 * jc;
                yr = fmaf(zr[j0], wv.x, yr);   yr = fmaf(-zi[j0], wv.y, yr);
                yi = fmaf(zr[j0], wv.y, yi);   yi = fmaf(zi[j0], wv.x, yi);
                yr = fmaf(zr[j0+1], wv.z, yr); yr = fmaf(-zi[j0+1], wv.w, yr);
                yi = fmaf(zr[j0+1], wv.w, yi); yi = fmaf(zi[j0+1], wv.z, yi);
            }
            Ar[swz(i, c)] = yr;
            Ai[swz(i, c)] = yi * sgn;
        }
    }
    __syncthreads();                           // BAR 2: inverse reads cross-wave

    pair1<-1>(Ar, Ai, reg, u);
    pair2<-1, false>(Ar, Ai, reg, u);          // full complex out, contiguous store
    // no barrier: gather below reads own-wave regions only

    // ---- store: gather rev4 positions; Re -> row b0, Im -> row b0+1
    const float4* b4 = (const float4*)bias;
    float* o0 = out + (size_t)b0 * 4096;
    float* o1 = out + (size_t)(b0 + 1) * 4096;
    int dbase = ((l >> 4) & 3) + (((l >> 2) & 3) << 2) + ((l & 3) << 4);
#pragma unroll
    for (int it = 0; it < 4; ++it) {
        int idx = 256 * w + 64 * it + l;
        int rg  = 4 * w + it;
        float v0[4], v1[4];
#pragma unroll
        for (int e = 0; e < 4; ++e) {
            int a = swz(rg, dbase + (e << 6));   // rev4(4l+e)
            v0[e] = Ar[a];
            v1[e] = Ai[a];
        }
        float4 bv = b4[idx];
        float4 ov0, ov1;
        ov0.x = v0[0] * (1.f / 256.f) + bv.x;
        ov0.y = v0[1] * (1.f / 256.f) + bv.y;
        ov0.z = v0[2] * (1.f / 256.f) + bv.z;
        ov0.w = v0[3] * (1.f / 256.f) + bv.w;
        ov1.x = v1[0] * (1.f / 256.f) + bv.x;
        ov1.y = v1[1] * (1.f / 256.f) + bv.y;
        ov1.z = v1[2] * (1.f / 256.f) + bv.z;
        ov1.w = v1[3] * (1.f / 256.f) + bv.w;
        ((float4*)o0)[idx] = ov0;
        ((float4*)o1)[idx] = ov1;
    }
}

extern "C" void kernel_launch(void* const* d_in, const int* in_sizes, int n_in,
                              void* d_out, int out_size, void* d_ws, size_t ws_size,
                              hipStream_t stream)
{
    const float* x    = (const float*)d_in[0];   // (8192, 4096)
    const float* W    = (const float*)d_in[1];   // (16, 16, 256)
    const float* d    = (const float*)d_in[2];   // (4096,)
    const float* bias = (const float*)d_in[3];   // (4096,)
    float* out = (float*)d_out;
    float* Wc4 = (float*)d_ws;                   // [16][8][132] float4 = 270 KB

    wfft_kernel<<<256, 256, 0, stream>>>(W, Wc4);
    bc_kernel<<<4096, 256, 0, stream>>>(x, d, bias, Wc4, out);
}